// Round 7
// baseline (1437.956 us; speedup 1.0000x reference)
//
#include <hip/hip_runtime.h>
#include <cmath>

constexpr int Bn = 16, RXn = 4, Cn = 128, Sn = 256, Dn = 128, Rn = 256;

typedef __attribute__((ext_vector_type(8))) short bf16x8;
typedef __attribute__((ext_vector_type(4))) float f32x4;
typedef unsigned short u16;
typedef unsigned int u32;
typedef __attribute__((ext_vector_type(4))) u16 u16x4;
typedef __attribute__((ext_vector_type(8))) u16 u16x8;
typedef __attribute__((ext_vector_type(2))) u32 u32x2;
typedef __attribute__((ext_vector_type(4))) u32 u32x4;

__device__ __forceinline__ u16 f2bf(float f) {
  union { float f; u32 u; } v; v.f = f;
  const u32 r = v.u + 0x7FFFu + ((v.u >> 16) & 1u);
  return (u16)(r >> 16);
}
__device__ __forceinline__ float bf2f(u16 h) {
  union { u32 u; float f; } v; v.u = (u32)h << 16; return v.f;
}
// HW pack-convert: lo -> bits[15:0], hi -> bits[31:16], RNE
__device__ __forceinline__ u32 cvtpk(float lo, float hi) {
  u32 r;
  asm("v_cvt_pk_bf16_f32 %0, %1, %2" : "=v"(r) : "v"(lo), "v"(hi));
  return r;
}
__device__ __forceinline__ void split2(float a, float b, u32& hi, u32& lo) {
  hi = cvtpk(a, b);
  union { u32 u; float f; } va, vb;
  va.u = hi << 16;
  vb.u = hi & 0xFFFF0000u;
  lo = cvtpk(a - va.f, b - vb.f);
}
__device__ __forceinline__ void ld8bf(const u16* __restrict__ p, float* v) {
  const u16x8 h = *(const u16x8*)p;
#pragma unroll
  for (int k = 0; k < 8; ++k) v[k] = bf2f(h[k]);
}

// ============================================================================
// Fused BN finalize: last producer block reduces `part` and writes stats.
// Consumers are unchanged (read precomputed stats) — avoids R1's failure mode
// of per-consumer scattered reads of atomic-written lines.
// nch must be a power of two <= 256.
// ============================================================================
__device__ void tail_finalize(const float* __restrict__ part,
                              int npart, int nch, float n,
                              const float* __restrict__ g,
                              const float* __restrict__ be,
                              float* __restrict__ stats,
                              u32* __restrict__ counter, u32 nblocks) {
  __shared__ u32 amlast;
  __shared__ float fr1[256], fr2[256];
  __threadfence();          // release this block's part writes (device scope)
  __syncthreads();
  if (threadIdx.x == 0)
    amlast = (atomicAdd(counter, 1u) == nblocks - 1u) ? 1u : 0u;
  __syncthreads();
  if (!amlast) return;
  __threadfence();          // acquire: all other blocks' part writes visible
  const int tpc = 256 / nch;
  const int t = threadIdx.x;
  const int ch = t / tpc;
  const int sl = t % tpc;
  float s1 = 0.f, s2 = 0.f;
  for (int i = sl; i < npart; i += tpc) {
    const float2 q = *(const float2*)&part[((size_t)ch * npart + i) * 2];
    s1 += q.x; s2 += q.y;
  }
  fr1[t] = s1; fr2[t] = s2;
  __syncthreads();
  for (int off = tpc >> 1; off; off >>= 1) {
    if (sl < off) { fr1[t] += fr1[t + off]; fr2[t] += fr2[t + off]; }
    __syncthreads();
  }
  if (sl == 0) {
    const float mean = fr1[t] / n;
    const float var  = fmaxf(fr2[t] / n - mean * mean, 0.f);
    const float inv  = rsqrtf(var + 1e-5f);
    const float sc   = inv * g[ch];
    stats[2 * ch + 0] = sc;
    stats[2 * ch + 1] = be[ch] - mean * sc;
  }
}

// ============================================================================
// Weight packing helper
// ============================================================================
__device__ __forceinline__ void pack_seg(const float* __restrict__ w, u16* __restrict__ wpk,
                                         int CIN, int COUT, int gid, int gsz) {
  const int total = COUT * CIN * 9;
  const int chunks = CIN >> 5;
  for (int idx = gid; idx < total; idx += gsz) {
    const int j = idx & 7;
    const int l = (idx >> 3) & 63;
    const int rest = idx >> 9;
    const int t = rest % 9;
    const int rest2 = rest / 9;
    const int q = rest2 % chunks;
    const int mf = rest2 / chunks;
    const int co = mf * 16 + (l & 15);
    const int ci = q * 32 + ((l >> 4) << 3) + j;
    wpk[idx] = f2bf(w[((size_t)co * CIN + ci) * 9 + t]);
  }
}

// ============================================================================
// Merged head kernel: blocks 0..127 = weight/DFT packing + counter zeroing;
// blocks 128..1151 = tp stats stage 1 (reads x). Disjoint in/out, no sync.
// ============================================================================
__global__ __launch_bounds__(256) void k_pack_stats(
    const float* __restrict__ e2w, const float* __restrict__ e3w,
    const float* __restrict__ d3w, const float* __restrict__ d2w,
    const float* __restrict__ d1w,
    const float* __restrict__ range_w, const float* __restrict__ dopp_w,
    u16* __restrict__ p_e2, u16* __restrict__ p_e3,
    u16* __restrict__ p_d3, u16* __restrict__ p_d2,
    u16* __restrict__ p_d1,
    u16* __restrict__ A1h, u16* __restrict__ A1l,
    u16* __restrict__ A2h, u16* __restrict__ A2l,
    const float* __restrict__ x, const float* __restrict__ w1,
    float* __restrict__ part, u32* __restrict__ cnts) {
  if (blockIdx.x < 128) {
    // ---- packing path ----
    const int gid = blockIdx.x * 256 + threadIdx.x;
    const int gsz = 128 * 256;
    if (gid < 16) cnts[gid] = 0u;   // zero tail-finalize counters (stream-ordered before users)
    pack_seg(e2w, p_e2, 32, 64, gid, gsz);
    pack_seg(e3w, p_e3, 64, 128, gid, gsz);
    pack_seg(d3w, p_d3, 128, 64, gid, gsz);
    pack_seg(d2w, p_d2, 64, 32, gid, gsz);
    pack_seg(d1w, p_d1, 32, 16, gid, gsz);
    for (int idx = gid; idx < 512 * 512; idx += gsz) {
      const int m = idx >> 9, k = idx & 511;
      const int r = m >> 1, p = m & 1, s = k >> 1, q = k & 1;
      const float Wr = range_w[((size_t)s * Rn + r) * 2 + 0];
      const float Wi = range_w[((size_t)s * Rn + r) * 2 + 1];
      const float v = (p == 0) ? ((q == 0) ? Wr : -Wi) : ((q == 0) ? Wi : Wr);
      const u16 h = f2bf(v);
      A1h[idx] = h;
      A1l[idx] = f2bf(v - bf2f(h));
    }
    for (int idx = gid; idx < 256 * 256; idx += gsz) {
      const int m = idx >> 8, k = idx & 255;
      const int d = m >> 1, p = m & 1, c = k >> 1, q = k & 1;
      const float Dr = dopp_w[((size_t)c * Dn + d) * 2 + 0];
      const float Di = dopp_w[((size_t)c * Dn + d) * 2 + 1];
      const float v = (p == 0) ? ((q == 0) ? Dr : -Di) : ((q == 0) ? Di : Dr);
      const u16 h = f2bf(v);
      A2h[idx] = h;
      A2l[idx] = f2bf(v - bf2f(h));
    }
    return;
  }
  // ---- tp stats1 path (1024 blocks) ----
  const int bx = blockIdx.x - 128;
  __shared__ float w1s[48];
  __shared__ float red8[8][4][2];
  const int t = threadIdx.x;
  if (t < 48) w1s[t] = w1[t];
  __syncthreads();
  float s1[8], s2[8];
#pragma unroll
  for (int o = 0; o < 8; ++o) { s1[o] = 0.f; s2[o] = 0.f; }
  for (int row = bx; row < Bn * RXn * Cn; row += 1024) {
    const float* xr = x + (size_t)row * Sn * 2;
    const float2 cc = *(const float2*)&xr[2 * t];
    const float2 mm = (t > 0) ? *(const float2*)&xr[2 * t - 2] : make_float2(0.f, 0.f);
    const float2 pp = (t < Sn - 1) ? *(const float2*)&xr[2 * t + 2] : make_float2(0.f, 0.f);
#pragma unroll
    for (int o = 0; o < 8; ++o) {
      const float* w = &w1s[o * 6];
      float h = w[0] * mm.x + w[1] * cc.x + w[2] * pp.x + w[3] * mm.y + w[4] * cc.y + w[5] * pp.y;
      s1[o] += h; s2[o] += h * h;
    }
  }
  const int lane = t & 63, wv = t >> 6;
#pragma unroll
  for (int o = 0; o < 8; ++o) {
    float v1 = s1[o], v2 = s2[o];
#pragma unroll
    for (int off = 32; off; off >>= 1) { v1 += __shfl_down(v1, off); v2 += __shfl_down(v2, off); }
    if (lane == 0) { red8[o][wv][0] = v1; red8[o][wv][1] = v2; }
  }
  __syncthreads();
  if (t < 8) {
    const float a1 = red8[t][0][0] + red8[t][1][0] + red8[t][2][0] + red8[t][3][0];
    const float a2 = red8[t][0][1] + red8[t][1][1] + red8[t][2][1] + red8[t][3][1];
    part[((size_t)t * 1024 + bx) * 2 + 0] = a1;
    part[((size_t)t * 1024 + bx) * 2 + 1] = a2;
  }
}

// Generic BN-stats finalize (only tp1 now — its producer shares the zeroing kernel)
__global__ __launch_bounds__(256) void k_finalize(const float* __restrict__ part, int npart,
                                                  float n, const float* __restrict__ g,
                                                  const float* __restrict__ be,
                                                  float* __restrict__ stats) {
  const int co = blockIdx.x, t = threadIdx.x;
  __shared__ float r1[256], r2[256];
  float s1 = 0.f, s2 = 0.f;
  for (int i = t; i < npart; i += 256) {
    s1 += part[((size_t)co * npart + i) * 2 + 0];
    s2 += part[((size_t)co * npart + i) * 2 + 1];
  }
  r1[t] = s1; r2[t] = s2;
  __syncthreads();
  for (int off = 128; off; off >>= 1) {
    if (t < off) { r1[t] += r1[t + off]; r2[t] += r2[t + off]; }
    __syncthreads();
  }
  if (t == 0) {
    const float mean = r1[0] / n;
    const float var  = fmaxf(r2[0] / n - mean * mean, 0.f);
    const float inv  = rsqrtf(var + 1e-5f);
    const float sc   = inv * g[co];
    stats[2 * co + 0] = sc;
    stats[2 * co + 1] = be[co] - mean * sc;
  }
}

// ============================================================================
// tp stage 2 fused: conv1 -> BN1 -> ReLU -> conv2; h2 stored packed bf16.
// tp2 finalize fused into tail (last block).
// ============================================================================
__global__ __launch_bounds__(256) void k_tp_fused2(const float* __restrict__ x,
                                                   const float* __restrict__ w1,
                                                   const float* __restrict__ st1,
                                                   const float* __restrict__ w2,
                                                   u32* __restrict__ h2p,
                                                   float* __restrict__ part,
                                                   const float* __restrict__ g2,
                                                   const float* __restrict__ be2,
                                                   float* __restrict__ st2,
                                                   u32* __restrict__ counter) {
  __shared__ float a1[8][Sn + 2];
  __shared__ float w1s[48], w2s[48], st[16];
  __shared__ float red2s[2][4][2];
  const int t = threadIdx.x;
  const int row = blockIdx.x;
  if (t < 48) { w1s[t] = w1[t]; w2s[t] = w2[t]; }
  if (t < 16) st[t] = st1[t];
  __syncthreads();
  const float* xr = x + (size_t)row * Sn * 2;
  const float2 cc = *(const float2*)&xr[2 * t];
  const float2 mm = (t > 0) ? *(const float2*)&xr[2 * t - 2] : make_float2(0.f, 0.f);
  const float2 pp = (t < Sn - 1) ? *(const float2*)&xr[2 * t + 2] : make_float2(0.f, 0.f);
#pragma unroll
  for (int o = 0; o < 8; ++o) {
    const float* w = &w1s[o * 6];
    float h = w[0] * mm.x + w[1] * cc.x + w[2] * pp.x + w[3] * mm.y + w[4] * cc.y + w[5] * pp.y;
    float v = fmaf(h, st[2 * o], st[2 * o + 1]);
    a1[o][1 + t] = v > 0.f ? v : 0.f;
    if (t == 0) { a1[o][0] = 0.f; a1[o][Sn + 1] = 0.f; }
  }
  __syncthreads();
  float h2v[2];
#pragma unroll
  for (int j = 0; j < 2; ++j) {
    float acc = 0.f;
#pragma unroll
    for (int o = 0; o < 8; ++o) {
      const float* w = &w2s[j * 24 + o * 3];
      acc += w[0] * a1[o][t] + w[1] * a1[o][t + 1] + w[2] * a1[o][t + 2];
    }
    h2v[j] = acc;
  }
  h2p[(size_t)row * Sn + t] = cvtpk(h2v[0], h2v[1]);
  const int lane = t & 63, wv = t >> 6;
#pragma unroll
  for (int j = 0; j < 2; ++j) {
    float v1 = h2v[j], v2 = h2v[j] * h2v[j];
#pragma unroll
    for (int off = 32; off; off >>= 1) { v1 += __shfl_down(v1, off); v2 += __shfl_down(v2, off); }
    if (lane == 0) { red2s[j][wv][0] = v1; red2s[j][wv][1] = v2; }
  }
  __syncthreads();
  if (t < 2) {
    const float a1s = red2s[t][0][0] + red2s[t][1][0] + red2s[t][2][0] + red2s[t][3][0];
    const float a2s = red2s[t][0][1] + red2s[t][1][1] + red2s[t][2][1] + red2s[t][3][1];
    part[((size_t)t * gridDim.x + row) * 2 + 0] = a1s;
    part[((size_t)t * gridDim.x + row) * 2 + 1] = a2s;
  }
  tail_finalize(part, gridDim.x, 2, 2097152.f, g2, be2, st2, counter, gridDim.x);
}

// ============================================================================
// DFT prep: BN2+ReLU+sumRX over packed-bf16 h2 -> B1 planes bf16 hi/lo
// ============================================================================
__global__ __launch_bounds__(256) void k_prep(const u32* __restrict__ h2p,
                                              const float* __restrict__ st2,
                                              u32* __restrict__ B1h32,
                                              u32* __restrict__ B1l32) {
  const int row = blockIdx.x;
  const int s = threadIdx.x;
  const int b = row >> 7, c = row & (Cn - 1);
  const float sc0 = st2[0], sh0 = st2[1], sc1 = st2[2], sh1 = st2[3];
  float xr = 0.f, xi = 0.f;
#pragma unroll
  for (int rx = 0; rx < RXn; ++rx) {
    const u32 v = h2p[(((size_t)b * RXn + rx) * Cn + c) * Sn + s];
    const float vr = bf2f((u16)(v & 0xFFFFu));
    const float vi = bf2f((u16)(v >> 16));
    xr += fmaxf(fmaf(vr, sc0, sh0), 0.f);
    xi += fmaxf(fmaf(vi, sc1, sh1), 0.f);
  }
  u32 hi, lo;
  split2(xr, xi, hi, lo);
  B1h32[(size_t)row * 256 + s] = hi;
  B1l32[(size_t)row * 256 + s] = lo;
}

// ============================================================================
// Split-bf16 MFMA GEMM (hi/lo, ~fp32): M32 x N64 tiles, K chunk 32.
// STORE=0: rng -> B2 planes; STORE=1: dop -> rd packed bf16 {re,im} u32
// ============================================================================
template <int M, int N, int K, int STORE>
__global__ __launch_bounds__(256) void k_gemm_split(const u16* __restrict__ Ah,
                                                    const u16* __restrict__ Al,
                                                    const u16* __restrict__ Bh,
                                                    const u16* __restrict__ Bl,
                                                    u32* __restrict__ out0,
                                                    u32* __restrict__ out1) {
  __shared__ __align__(16) u16 lah[32 * 40], lal[32 * 40];
  __shared__ __align__(16) u16 lbh[64 * 40], lbl[64 * 40];
  const int tid = threadIdx.x;
  const int lane = tid & 63, wid = tid >> 6;
  const int wm = wid >> 1, wn = wid & 1;
  const int l15 = lane & 15, lg = lane >> 4;
  const int m0 = blockIdx.x * 32, n0 = blockIdx.y * 64;
  f32x4 acc[2];
  acc[0] = (f32x4){0.f, 0.f, 0.f, 0.f};
  acc[1] = (f32x4){0.f, 0.f, 0.f, 0.f};
  const int arow = tid >> 3, ak = (tid & 7) * 4;
  const int brow = tid >> 2, bk = (tid & 3) * 8;
  for (int k0 = 0; k0 < K; k0 += 32) {
    *(u16x4*)&lah[arow * 40 + ak] = *(const u16x4*)&Ah[(size_t)(m0 + arow) * K + k0 + ak];
    *(u16x4*)&lal[arow * 40 + ak] = *(const u16x4*)&Al[(size_t)(m0 + arow) * K + k0 + ak];
    *(u16x8*)&lbh[brow * 40 + bk] = *(const u16x8*)&Bh[(size_t)(n0 + brow) * K + k0 + bk];
    *(u16x8*)&lbl[brow * 40 + bk] = *(const u16x8*)&Bl[(size_t)(n0 + brow) * K + k0 + bk];
    __syncthreads();
    const bf16x8 ah = *(const bf16x8*)&lah[(wm * 16 + l15) * 40 + lg * 8];
    const bf16x8 al = *(const bf16x8*)&lal[(wm * 16 + l15) * 40 + lg * 8];
#pragma unroll
    for (int f = 0; f < 2; ++f) {
      const bf16x8 bh = *(const bf16x8*)&lbh[(wn * 32 + f * 16 + l15) * 40 + lg * 8];
      const bf16x8 bl = *(const bf16x8*)&lbl[(wn * 32 + f * 16 + l15) * 40 + lg * 8];
      acc[f] = __builtin_amdgcn_mfma_f32_16x16x32_bf16(ah, bh, acc[f], 0, 0, 0);
      acc[f] = __builtin_amdgcn_mfma_f32_16x16x32_bf16(ah, bl, acc[f], 0, 0, 0);
      acc[f] = __builtin_amdgcn_mfma_f32_16x16x32_bf16(al, bh, acc[f], 0, 0, 0);
    }
    __syncthreads();
  }
  const int mb = m0 + wm * 16 + lg * 4;
#pragma unroll
  for (int f = 0; f < 2; ++f) {
    const int n = n0 + wn * 32 + f * 16 + l15;
    if (STORE == 0) {
      const int b = n >> 7, c = n & 127;
#pragma unroll
      for (int pair = 0; pair < 2; ++pair) {
        const int r = (mb >> 1) + pair;
        u32 hi, lo;
        split2(acc[f][2 * pair], acc[f][2 * pair + 1], hi, lo);
        const size_t idx = ((size_t)b * 256 + r) * 128 + c;
        out0[idx] = hi;
        out1[idx] = lo;
      }
    } else {
      const int b = n >> 8, r = n & 255;
#pragma unroll
      for (int pair = 0; pair < 2; ++pair) {
        const int d = (mb >> 1) + pair;
        out0[((size_t)b * 128 + d) * 256 + r] = cvtpk(acc[f][2 * pair], acc[f][2 * pair + 1]);
      }
    }
  }
}

// ============================================================================
// MFMA implicit-GEMM 3x3 conv (pad 1), NHWC bf16 activations (raw), fused:
//   MODE 1: bnrelu(in)                            (dec3)
//   MODE 2: bnrelu(2x2 maxpool of raw)            (enc2, enc3)
//   MODE 3: up2(bnrelu(in @ H/2 x W/2)) + bnrelu(in2 @ H x W)  (dec2, dec1)
// MODE 3: two-phase in-LDS dedup (bnrelu(lowres) once per region pixel, padded
// stride 36 to avoid bank conflicts). Output BN finalize fused into tail.
// ============================================================================
template <int CIN, int COUT, int H, int W, int TH, int TW, int MW, int NW,
          int WAVES_M, int WAVES_N, int MODE>
__global__ __launch_bounds__(256) void k_conv_mfma(const u16* __restrict__ in,
                                                   const u16* __restrict__ wpk,
                                                   const float* __restrict__ in_stats,
                                                   const u16* __restrict__ in2,
                                                   const float* __restrict__ in2_stats,
                                                   u16* __restrict__ out,
                                                   float* __restrict__ part,
                                                   const float* __restrict__ gg,
                                                   const float* __restrict__ bb,
                                                   float nn,
                                                   float* __restrict__ stats_out,
                                                   u32* __restrict__ counter) {
  constexpr int COG = WAVES_M * MW * 16;
  constexpr int CHUNKS = CIN / 32;
  constexpr int NFROW = TW / 16;
  constexpr int XROWS = TH + 2, XCOLS = TW + 2;
  // MODE 3 support region (TH=8, TW=32, scale ~0.5): rows <= 7, cols <= 19
  constexpr int RR = 7, RC = 19;
  constexpr int RSTRIDE = 36;  // floats per region pixel (pad 32->36: kills bank conflicts)
  static_assert(WAVES_M * WAVES_N == 4, "waves");
  static_assert(WAVES_N * NW * 16 == TH * TW, "pixel cover");
  static_assert(MODE != 3 || (TH == 8 && TW == 32), "region sized for 8x32");
  __shared__ __align__(16) u16 xs[XROWS * XCOLS * 40];
  __shared__ float red1[WAVES_N][COG], red2[WAVES_N][COG];
  __shared__ __align__(16) float sst1[2 * CIN];
  __shared__ __align__(16) float sst2[(MODE == 3) ? 2 * CIN : 4];
  __shared__ __align__(16) float reg_lds[(MODE == 3) ? RR * RC * RSTRIDE : 4];
  const int tid = threadIdx.x;
  const int lane = tid & 63;
  const int wid = tid >> 6;
  const int wave_m = wid / WAVES_N;
  const int wave_n = wid % WAVES_N;
  const int l15 = lane & 15, lg = lane >> 4;
  constexpr int TILES_W = W / TW;
  const int tile = blockIdx.x;
  const int tw = tile % TILES_W, th = tile / TILES_W;
  const int h0 = th * TH, w0 = tw * TW;
  const int cog = blockIdx.y, b = blockIdx.z;
  // preload BN stats into LDS (one barrier; bit-identical copy)
  for (int i = tid; i < 2 * CIN; i += 256) sst1[i] = in_stats[i];
  if (MODE == 3)
    for (int i = tid; i < 2 * CIN; i += 256) sst2[i] = in2_stats[i];
  __syncthreads();
  f32x4 acc[MW][NW];
#pragma unroll
  for (int m = 0; m < MW; ++m)
#pragma unroll
    for (int f = 0; f < NW; ++f) acc[m][f] = (f32x4){0.f, 0.f, 0.f, 0.f};

  for (int q = 0; q < CHUNKS; ++q) {
    // ---- hoisted BN stats (thread-invariant within the item loops) ----
    const int ci0 = (tid & 3) * 8;
    const int cch = q * 32 + ci0;
    float sc[8], sh[8];
#pragma unroll
    for (int k = 0; k < 4; ++k) {
      const float4 qq = *(const float4*)&sst1[2 * cch + 4 * k];
      sc[2 * k] = qq.x; sh[2 * k] = qq.y; sc[2 * k + 1] = qq.z; sh[2 * k + 1] = qq.w;
    }
    float ec[8], es[8];
    if constexpr (MODE == 3) {
#pragma unroll
      for (int k = 0; k < 4; ++k) {
        const float4 qq = *(const float4*)&sst2[2 * cch + 4 * k];
        ec[2 * k] = qq.x; es[2 * k] = qq.y; ec[2 * k + 1] = qq.z; es[2 * k + 1] = qq.w;
      }
    }
    if constexpr (MODE == 3) {
      constexpr int Hi2 = H / 2, Wi2 = W / 2;
      constexpr float steph = (float)(Hi2 - 1) / (float)(H - 1);
      constexpr float stepw = (float)(Wi2 - 1) / (float)(W - 1);
      const int gh_min = (h0 - 1 > 0) ? h0 - 1 : 0;
      const int gw_min = (w0 - 1 > 0) ? w0 - 1 : 0;
      const int lo0 = (int)((float)gh_min * steph);
      const int lw0 = (int)((float)gw_min * stepw);
      // ---- phase A: bnrelu(low-res) once per region pixel -> f32 LDS ----
      for (int i = tid; i < RR * RC * 4; i += 256) {
        const int pixr = i >> 2;
        const int rcc = pixr % RC;
        const int rrr = pixr / RC;
        const int lr = (lo0 + rrr < Hi2 - 1) ? lo0 + rrr : Hi2 - 1;
        const int lc = (lw0 + rcc < Wi2 - 1) ? lw0 + rcc : Wi2 - 1;
        float tv[8];
        ld8bf(&in[(((size_t)b * Hi2 + lr) * Wi2 + lc) * CIN + cch], tv);
#pragma unroll
        for (int k = 0; k < 8; ++k) tv[k] = fmaxf(fmaf(tv[k], sc[k], sh[k]), 0.f);
        *(float4*)&reg_lds[(rrr * RC + rcc) * RSTRIDE + ci0] = *(float4*)&tv[0];
        *(float4*)&reg_lds[(rrr * RC + rcc) * RSTRIDE + ci0 + 4] = *(float4*)&tv[4];
      }
      __syncthreads();
      // ---- phase B: lerp from LDS + skip bnrelu -> xs ----
      for (int i = tid; i < XROWS * XCOLS * 4; i += 256) {
        const int pix = i >> 2;
        const int col = pix % XCOLS;
        const int row = pix / XCOLS;
        const int gh = h0 + row - 1, gw = w0 + col - 1;
        u32x4 enc = (u32x4){0u, 0u, 0u, 0u};
        if (gh >= 0 && gh < H && gw >= 0 && gw < W) {
          const float ph = (float)gh * steph;
          const int hlo = (int)ph;
          const float fh = ph - (float)hlo;
          const int hhi = (hlo + 1 < Hi2) ? hlo + 1 : Hi2 - 1;
          const float pw = (float)gw * stepw;
          const int wl = (int)pw;
          const float fw = pw - (float)wl;
          const int wh = (wl + 1 < Wi2) ? wl + 1 : Wi2 - 1;
          const float w00 = (1.f - fh) * (1.f - fw), w01 = (1.f - fh) * fw;
          const float w10 = fh * (1.f - fw), w11 = fh * fw;
          const float* p00 = &reg_lds[((hlo - lo0) * RC + (wl - lw0)) * RSTRIDE + ci0];
          const float* p01 = &reg_lds[((hlo - lo0) * RC + (wh - lw0)) * RSTRIDE + ci0];
          const float* p10 = &reg_lds[((hhi - lo0) * RC + (wl - lw0)) * RSTRIDE + ci0];
          const float* p11 = &reg_lds[((hhi - lo0) * RC + (wh - lw0)) * RSTRIDE + ci0];
          float ev[8];
          ld8bf(&in2[(((size_t)b * H + gh) * W + gw) * CIN + cch], ev);
          float vv[8];
#pragma unroll
          for (int k = 0; k < 8; ++k) {
            vv[k] = w00 * p00[k] + w01 * p01[k] + w10 * p10[k] + w11 * p11[k]
                  + fmaxf(fmaf(ev[k], ec[k], es[k]), 0.f);
          }
#pragma unroll
          for (int j = 0; j < 4; ++j) enc[j] = cvtpk(vv[2 * j], vv[2 * j + 1]);
        }
        *(u32x4*)&xs[(row * XCOLS + col) * 40 + ci0] = enc;
      }
    } else {
      for (int i = tid; i < XROWS * XCOLS * 4; i += 256) {
        const int pix = i >> 2;
        const int col = pix % XCOLS;
        const int row = pix / XCOLS;
        const int gh = h0 + row - 1, gw = w0 + col - 1;
        u32x4 enc = (u32x4){0u, 0u, 0u, 0u};
        if (gh >= 0 && gh < H && gw >= 0 && gw < W) {
          float vv[8];
          if constexpr (MODE == 1) {
            float tv[8];
            ld8bf(&in[(((size_t)b * H + gh) * W + gw) * CIN + cch], tv);
#pragma unroll
            for (int k = 0; k < 8; ++k) vv[k] = fmaxf(fmaf(tv[k], sc[k], sh[k]), 0.f);
          } else {
            // MODE 2: max of raw taps first, then single BN+ReLU (sc > 0)
            const size_t rs = (size_t)(2 * W) * CIN;
            const u16* pb = &in[(((size_t)b * 2 * H + 2 * gh) * (2 * W) + 2 * gw) * CIN + cch];
            float tp[4][8];
            ld8bf(pb, tp[0]);
            ld8bf(pb + CIN, tp[1]);
            ld8bf(pb + rs, tp[2]);
            ld8bf(pb + rs + CIN, tp[3]);
#pragma unroll
            for (int k = 0; k < 8; ++k) {
              const float mx = fmaxf(fmaxf(tp[0][k], tp[1][k]), fmaxf(tp[2][k], tp[3][k]));
              vv[k] = fmaxf(fmaf(mx, sc[k], sh[k]), 0.f);
            }
          }
#pragma unroll
          for (int j = 0; j < 4; ++j) enc[j] = cvtpk(vv[2 * j], vv[2 * j + 1]);
        }
        *(u32x4*)&xs[(row * XCOLS + col) * 40 + ci0] = enc;
      }
    }
    __syncthreads();
#pragma unroll
    for (int t = 0; t < 9; ++t) {
      const int ky = t / 3, kx = t % 3;
      bf16x8 afr[MW];
#pragma unroll
      for (int m = 0; m < MW; ++m) {
        const int mfg = cog * (COG / 16) + wave_m * MW + m;
        afr[m] = *(const bf16x8*)&wpk[((((size_t)mfg * CHUNKS + q) * 9 + t) * 64 + lane) * 8];
      }
      bf16x8 bfr[NW];
#pragma unroll
      for (int f = 0; f < NW; ++f) {
        const int nf = wave_n * NW + f;
        const int r = nf / NFROW;
        const int cseg = (nf % NFROW) * 16;
        bfr[f] = *(const bf16x8*)&xs[((r + ky) * XCOLS + (cseg + l15 + kx)) * 40 + lg * 8];
      }
#pragma unroll
      for (int m = 0; m < MW; ++m)
#pragma unroll
        for (int f = 0; f < NW; ++f)
          acc[m][f] = __builtin_amdgcn_mfma_f32_16x16x32_bf16(afr[m], bfr[f], acc[m][f], 0, 0, 0);
    }
    __syncthreads();
  }

#pragma unroll
  for (int m = 0; m < MW; ++m) {
    const int cobase = cog * COG + (wave_m * MW + m) * 16 + lg * 4;
#pragma unroll
    for (int f = 0; f < NW; ++f) {
      const int nf = wave_n * NW + f;
      const int r = nf / NFROW;
      const int cseg = (nf % NFROW) * 16;
      u16* op = out + (((size_t)b * H + h0 + r) * W + (w0 + cseg + l15)) * COUT + cobase;
      u32x2 ov;
      ov[0] = cvtpk(acc[m][f][0], acc[m][f][1]);
      ov[1] = cvtpk(acc[m][f][2], acc[m][f][3]);
      *(u32x2*)op = ov;
    }
  }
#pragma unroll
  for (int m = 0; m < MW; ++m)
#pragma unroll
    for (int reg = 0; reg < 4; ++reg) {
      float s1 = 0.f, s2 = 0.f;
#pragma unroll
      for (int f = 0; f < NW; ++f) { const float v = acc[m][f][reg]; s1 += v; s2 += v * v; }
#pragma unroll
      for (int off = 1; off < 16; off <<= 1) { s1 += __shfl_xor(s1, off); s2 += __shfl_xor(s2, off); }
      if (l15 == 0) {
        const int ch = (wave_m * MW + m) * 16 + lg * 4 + reg;
        red1[wave_n][ch] = s1; red2[wave_n][ch] = s2;
      }
    }
  __syncthreads();
  const int npart = gridDim.x * gridDim.z;
  if (tid < COG) {
    float s1 = 0.f, s2 = 0.f;
#pragma unroll
    for (int wn = 0; wn < WAVES_N; ++wn) { s1 += red1[wn][tid]; s2 += red2[wn][tid]; }
    const int pidx = blockIdx.z * gridDim.x + blockIdx.x;
    part[((size_t)(cog * COG + tid) * npart + pidx) * 2 + 0] = s1;
    part[((size_t)(cog * COG + tid) * npart + pidx) * 2 + 1] = s2;
  }
  tail_finalize(part, npart, gridDim.y * COG, nn, gg, bb, stats_out, counter,
                gridDim.x * gridDim.y * gridDim.z);
}

// ============================================================================
// enc1 direct fp32 conv: packed-bf16 rd in (C=2) -> NHWC out (C=32 bf16)
// e1 BN finalize fused into tail.
// ============================================================================
__global__ __launch_bounds__(256) void k_conv1(const u32* __restrict__ in,
                                               const float* __restrict__ wgt,
                                               u16* __restrict__ out,
                                               float* __restrict__ part,
                                               const float* __restrict__ g1,
                                               const float* __restrict__ b1,
                                               float* __restrict__ st1,
                                               u32* __restrict__ counter) {
  constexpr int H = 128, W = 256, TW = 64, TH = 16, COG = 16, COUT = 32;
  const int tid = threadIdx.x;
  const int tile = blockIdx.x;
  const int tw = tile & 3, th = tile >> 2;
  const int cog = blockIdx.y, b = blockIdx.z;
  const int ty = tid >> 4;
  const int wofs = (tid & 15) * 4;
  const int h0 = th * TH, w0t = tw * TW;
  __shared__ float xs0[TH + 2][TW + 3], xs1[TH + 2][TW + 3];
  __shared__ float ws[2][COG][12];
  __shared__ float redp[4][COG], redq[4][COG];
  for (int i = tid; i < 2 * COG * 9; i += 256) {
    const int tap = i % 9, rest = i / 9;
    const int ci = rest & 1, co = rest >> 1;
    ws[ci][co][tap] = wgt[((size_t)(cog * COG + co) * 2 + ci) * 9 + tap];
  }
  for (int i = tid; i < (TH + 2) * (TW + 2); i += 256) {
    const int col = i % (TW + 2), row = i / (TW + 2);
    const int gh = h0 + row - 1, gw = w0t + col - 1;
    float v0 = 0.f, v1 = 0.f;
    if (gh >= 0 && gh < H && gw >= 0 && gw < W) {
      const u32 v = in[((size_t)b * H + gh) * W + gw];
      v0 = bf2f((u16)(v & 0xFFFFu));
      v1 = bf2f((u16)(v >> 16));
    }
    xs0[row][col] = v0; xs1[row][col] = v1;
  }
  __syncthreads();
  float acc[4][COG];
#pragma unroll
  for (int px = 0; px < 4; ++px)
#pragma unroll
    for (int co = 0; co < COG; ++co) acc[px][co] = 0.f;
#pragma unroll
  for (int ci = 0; ci < 2; ++ci) {
    float xrow[3][6];
#pragma unroll
    for (int ky = 0; ky < 3; ++ky)
#pragma unroll
      for (int j = 0; j < 6; ++j)
        xrow[ky][j] = ci ? xs1[ty + ky][wofs + j] : xs0[ty + ky][wofs + j];
#pragma unroll
    for (int co = 0; co < COG; ++co) {
      const float4 wq0 = *(const float4*)&ws[ci][co][0];
      const float4 wq1 = *(const float4*)&ws[ci][co][4];
      const float  w8 = ws[ci][co][8];
      const float wv[9] = {wq0.x, wq0.y, wq0.z, wq0.w, wq1.x, wq1.y, wq1.z, wq1.w, w8};
#pragma unroll
      for (int ky = 0; ky < 3; ++ky)
#pragma unroll
        for (int kx = 0; kx < 3; ++kx)
#pragma unroll
          for (int px = 0; px < 4; ++px)
            acc[px][co] = fmaf(xrow[ky][px + kx], wv[ky * 3 + kx], acc[px][co]);
    }
  }
#pragma unroll
  for (int px = 0; px < 4; ++px) {
    u16* op = out + (((size_t)b * H + h0 + ty) * W + (w0t + wofs + px)) * COUT + cog * COG;
    u32x4 ov;
    ov[0] = cvtpk(acc[px][0], acc[px][1]);
    ov[1] = cvtpk(acc[px][2], acc[px][3]);
    ov[2] = cvtpk(acc[px][4], acc[px][5]);
    ov[3] = cvtpk(acc[px][6], acc[px][7]);
    *(u32x4*)&op[0] = ov;
    u32x4 ov2;
    ov2[0] = cvtpk(acc[px][8], acc[px][9]);
    ov2[1] = cvtpk(acc[px][10], acc[px][11]);
    ov2[2] = cvtpk(acc[px][12], acc[px][13]);
    ov2[3] = cvtpk(acc[px][14], acc[px][15]);
    *(u32x4*)&op[8] = ov2;
  }
  const int lane = tid & 63, wid = tid >> 6;
#pragma unroll
  for (int co = 0; co < COG; ++co) {
    float v1 = 0.f, v2 = 0.f;
#pragma unroll
    for (int px = 0; px < 4; ++px) { v1 += acc[px][co]; v2 += acc[px][co] * acc[px][co]; }
#pragma unroll
    for (int off = 32; off; off >>= 1) { v1 += __shfl_down(v1, off); v2 += __shfl_down(v2, off); }
    if (lane == 0) { redp[wid][co] = v1; redq[wid][co] = v2; }
  }
  __syncthreads();
  const int npart = gridDim.x * gridDim.z;
  if (tid < COG) {
    const int pidx = blockIdx.z * gridDim.x + blockIdx.x;
    part[((size_t)(cog * COG + tid) * npart + pidx) * 2 + 0] = redp[0][tid] + redp[1][tid] + redp[2][tid] + redp[3][tid];
    part[((size_t)(cog * COG + tid) * npart + pidx) * 2 + 1] = redq[0][tid] + redq[1][tid] + redq[2][tid] + redq[3][tid];
  }
  tail_finalize(part, npart, gridDim.y * COG, 524288.f, g1, b1, st1, counter,
                gridDim.x * gridDim.y * gridDim.z);
}

// final: bnrelu(d1 bf16) -> 1x1 conv (16->1) + bias + sigmoid
__global__ __launch_bounds__(256) void k_out_bn(const u16* __restrict__ d1,
                                                const float* __restrict__ st,
                                                const float* __restrict__ ow,
                                                const float* __restrict__ ob,
                                                float* __restrict__ out) {
  const size_t i = (size_t)blockIdx.x * 256 + threadIdx.x;
  const size_t total = (size_t)Bn * Dn * Rn;
  if (i >= total) return;
  const u16* p = d1 + i * 16;
  float v[16];
  ld8bf(p, v);
  ld8bf(p + 8, v + 8);
  float acc = ob[0];
#pragma unroll
  for (int k = 0; k < 16; ++k) {
    const float2 q = *(const float2*)&st[2 * k];
    acc += fmaxf(fmaf(v[k], q.x, q.y), 0.f) * ow[k];
  }
  out[i] = 1.f / (1.f + expf(-acc));
}

// ============================================================================
extern "C" void kernel_launch(void* const* d_in, const int* in_sizes, int n_in,
                              void* d_out, int out_size, void* d_ws, size_t ws_size,
                              hipStream_t stream) {
  (void)in_sizes; (void)n_in; (void)out_size; (void)ws_size;
  const float* x       = (const float*)d_in[0];
  const float* tp_w1   = (const float*)d_in[1];
  const float* tp_g1   = (const float*)d_in[3];
  const float* tp_be1  = (const float*)d_in[4];
  const float* tp_w2   = (const float*)d_in[5];
  const float* tp_g2   = (const float*)d_in[7];
  const float* tp_be2  = (const float*)d_in[8];
  const float* range_w = (const float*)d_in[9];
  const float* dopp_w  = (const float*)d_in[10];
  const float* e1w = (const float*)d_in[11]; const float* e1g = (const float*)d_in[13]; const float* e1b = (const float*)d_in[14];
  const float* e2w = (const float*)d_in[15]; const float* e2g = (const float*)d_in[17]; const float* e2b = (const float*)d_in[18];
  const float* e3w = (const float*)d_in[19]; const float* e3g = (const float*)d_in[21]; const float* e3b = (const float*)d_in[22];
  const float* d3w = (const float*)d_in[23]; const float* d3g = (const float*)d_in[25]; const float* d3b = (const float*)d_in[26];
  const float* d2w = (const float*)d_in[27]; const float* d2g = (const float*)d_in[29]; const float* d2b = (const float*)d_in[30];
  const float* d1w = (const float*)d_in[31]; const float* d1g = (const float*)d_in[33]; const float* d1b = (const float*)d_in[34];
  const float* out_w = (const float*)d_in[35];
  const float* out_b = (const float*)d_in[36];
  float* outp = (float*)d_out;

  // -------- workspace arena; U-Net raw tensors bf16 NHWC --------
  float* W  = (float*)d_ws;
  u16* Ae1  = (u16*)W;
  float* Bx = W + 16777216;
  u16* Ce2  = (u16*)(W + 33554432);
  u16* Ee3  = (u16*)(W + 41943040);
  u16* Fd3  = (u16*)(W + 46137344);
  float* part  = W + 48234496;
  float* stats = part + 262144;
  u16* wpk_e2 = (u16*)(stats + 1024);
  u16* wpk_e3 = wpk_e2 + 18432;
  u16* wpk_d3 = wpk_e3 + 73728;
  u16* wpk_d2 = wpk_d3 + 73728;
  u16* wpk_d1 = wpk_d2 + 18432;
  u16* A1h = wpk_d1 + 4608;
  u16* A1l = A1h + 262144;
  u16* A2h = A1l + 262144;
  u16* A2l = A2h + 65536;
  u16* B1h = A2l + 65536;
  u16* B1l = B1h + 1048576;
  u16* B2h = B1l + 1048576;
  u16* B2l = B2h + 1048576;

  u32* h2p = (u32*)Bx;                         // [8192][256] packed bf16 pairs (8MB)
  u32* rd  = (u32*)(Bx + 2097152 + 65536);     // [b][128][256] packed {re,im} (2MB)
  u16* d1  = (u16*)Bx;                         // [b][128][256][16] bf16 (h2p/rd dead)

  float* st_tp1 = stats;
  float* st_tp2 = stats + 16;
  float* st_e1  = stats + 32;
  float* st_e2  = stats + 96;
  float* st_e3  = stats + 224;
  float* st_d3  = stats + 480;
  float* st_d2  = stats + 608;
  float* st_d1  = stats + 672;
  u32*   cnts   = (u32*)(stats + 768);         // 16 tail-finalize counters

  const float Ntp = 2097152.f;

  // ---- merged head: weight packing + counter zeroing (0-127) || tp stats1 ----
  k_pack_stats<<<1152, 256, 0, stream>>>(e2w, e3w, d3w, d2w, d1w, range_w, dopp_w,
                                         wpk_e2, wpk_e3, wpk_d3, wpk_d2, wpk_d1,
                                         A1h, A1l, A2h, A2l,
                                         x, tp_w1, part, cnts);
  k_finalize<<<8, 256, 0, stream>>>(part, 1024, Ntp, tp_g1, tp_be1, st_tp1);
  k_tp_fused2<<<Bn * RXn * Cn, 256, 0, stream>>>(x, tp_w1, st_tp1, tp_w2, h2p, part,
                                                 tp_g2, tp_be2, st_tp2, cnts + 0);

  // ---- DFTs via split-bf16 MFMA GEMMs ----
  k_prep<<<Bn * Cn, 256, 0, stream>>>(h2p, st_tp2, (u32*)B1h, (u32*)B1l);
  k_gemm_split<512, 2048, 512, 0><<<dim3(16, 32), 256, 0, stream>>>(
      A1h, A1l, B1h, B1l, (u32*)B2h, (u32*)B2l);
  k_gemm_split<256, 4096, 256, 1><<<dim3(8, 64), 256, 0, stream>>>(
      A2h, A2l, B2h, B2l, rd, nullptr);

  // ---- U-Net (BN finalizes fused into producer tails) ----
  k_conv1<<<dim3(32, 2, Bn), 256, 0, stream>>>(rd, e1w, Ae1, part,
                                               e1g, e1b, st_e1, cnts + 1);
  k_conv_mfma<32, 64, 64, 128, 8, 32, 2, 8, 2, 2, 2><<<dim3(32, 1, Bn), 256, 0, stream>>>(
      Ae1, wpk_e2, st_e1, nullptr, nullptr, Ce2, part,
      e2g, e2b, 131072.f, st_e2, cnts + 2);
  k_conv_mfma<64, 128, 32, 64, 4, 16, 1, 4, 4, 1, 2><<<dim3(32, 2, Bn), 256, 0, stream>>>(
      Ce2, wpk_e3, st_e2, nullptr, nullptr, Ee3, part,
      e3g, e3b, 32768.f, st_e3, cnts + 3);
  k_conv_mfma<128, 64, 32, 64, 4, 16, 1, 4, 4, 1, 1><<<dim3(32, 1, Bn), 256, 0, stream>>>(
      Ee3, wpk_d3, st_e3, nullptr, nullptr, Fd3, part,
      d3g, d3b, 32768.f, st_d3, cnts + 4);
  k_conv_mfma<64, 32, 64, 128, 8, 32, 1, 8, 2, 2, 3><<<dim3(32, 1, Bn), 256, 0, stream>>>(
      Fd3, wpk_d2, st_d3, Ce2, st_e2, Ee3, part,
      d2g, d2b, 131072.f, st_d2, cnts + 5);
  k_conv_mfma<32, 16, 128, 256, 8, 32, 1, 4, 1, 4, 3><<<dim3(128, 1, Bn), 256, 0, stream>>>(
      Ee3, wpk_d1, st_d2, Ae1, st_e1, d1, part,
      d1g, d1b, 524288.f, st_d1, cnts + 6);
  k_out_bn<<<2048, 256, 0, stream>>>(d1, st_d1, out_w, out_b, outp);
}

// Round 8
// 211.379 us; speedup vs baseline: 6.8027x; 6.8027x over previous
//
#include <hip/hip_runtime.h>
#include <cmath>

constexpr int Bn = 16, RXn = 4, Cn = 128, Sn = 256, Dn = 128, Rn = 256;

typedef __attribute__((ext_vector_type(8))) short bf16x8;
typedef __attribute__((ext_vector_type(4))) float f32x4;
typedef unsigned short u16;
typedef unsigned int u32;
typedef __attribute__((ext_vector_type(4))) u16 u16x4;
typedef __attribute__((ext_vector_type(8))) u16 u16x8;
typedef __attribute__((ext_vector_type(2))) u32 u32x2;
typedef __attribute__((ext_vector_type(4))) u32 u32x4;

__device__ __forceinline__ u16 f2bf(float f) {
  union { float f; u32 u; } v; v.f = f;
  const u32 r = v.u + 0x7FFFu + ((v.u >> 16) & 1u);
  return (u16)(r >> 16);
}
__device__ __forceinline__ float bf2f(u16 h) {
  union { u32 u; float f; } v; v.u = (u32)h << 16; return v.f;
}
// HW pack-convert: lo -> bits[15:0], hi -> bits[31:16], RNE
__device__ __forceinline__ u32 cvtpk(float lo, float hi) {
  u32 r;
  asm("v_cvt_pk_bf16_f32 %0, %1, %2" : "=v"(r) : "v"(lo), "v"(hi));
  return r;
}
__device__ __forceinline__ void split2(float a, float b, u32& hi, u32& lo) {
  hi = cvtpk(a, b);
  union { u32 u; float f; } va, vb;
  va.u = hi << 16;
  vb.u = hi & 0xFFFF0000u;
  lo = cvtpk(a - va.f, b - vb.f);
}
__device__ __forceinline__ void ld8bf(const u16* __restrict__ p, float* v) {
  const u16x8 h = *(const u16x8*)p;
#pragma unroll
  for (int k = 0; k < 8; ++k) v[k] = bf2f(h[k]);
}

// ============================================================================
// Weight packing helper
// ============================================================================
__device__ __forceinline__ void pack_seg(const float* __restrict__ w, u16* __restrict__ wpk,
                                         int CIN, int COUT, int gid, int gsz) {
  const int total = COUT * CIN * 9;
  const int chunks = CIN >> 5;
  for (int idx = gid; idx < total; idx += gsz) {
    const int j = idx & 7;
    const int l = (idx >> 3) & 63;
    const int rest = idx >> 9;
    const int t = rest % 9;
    const int rest2 = rest / 9;
    const int q = rest2 % chunks;
    const int mf = rest2 / chunks;
    const int co = mf * 16 + (l & 15);
    const int ci = q * 32 + ((l >> 4) << 3) + j;
    wpk[idx] = f2bf(w[((size_t)co * CIN + ci) * 9 + t]);
  }
}

// ============================================================================
// Merged head kernel: blocks 0..127 = weight/DFT packing (independent of x);
// blocks 128..1151 = tp stats stage 1 (reads x). Disjoint in/out, no sync.
// ============================================================================
__global__ __launch_bounds__(256) void k_pack_stats(
    const float* __restrict__ e2w, const float* __restrict__ e3w,
    const float* __restrict__ d3w, const float* __restrict__ d2w,
    const float* __restrict__ d1w,
    const float* __restrict__ range_w, const float* __restrict__ dopp_w,
    u16* __restrict__ p_e2, u16* __restrict__ p_e3,
    u16* __restrict__ p_d3, u16* __restrict__ p_d2,
    u16* __restrict__ p_d1,
    u16* __restrict__ A1h, u16* __restrict__ A1l,
    u16* __restrict__ A2h, u16* __restrict__ A2l,
    const float* __restrict__ x, const float* __restrict__ w1,
    float* __restrict__ part) {
  if (blockIdx.x < 128) {
    // ---- packing path ----
    const int gid = blockIdx.x * 256 + threadIdx.x;
    const int gsz = 128 * 256;
    pack_seg(e2w, p_e2, 32, 64, gid, gsz);
    pack_seg(e3w, p_e3, 64, 128, gid, gsz);
    pack_seg(d3w, p_d3, 128, 64, gid, gsz);
    pack_seg(d2w, p_d2, 64, 32, gid, gsz);
    pack_seg(d1w, p_d1, 32, 16, gid, gsz);
    for (int idx = gid; idx < 512 * 512; idx += gsz) {
      const int m = idx >> 9, k = idx & 511;
      const int r = m >> 1, p = m & 1, s = k >> 1, q = k & 1;
      const float Wr = range_w[((size_t)s * Rn + r) * 2 + 0];
      const float Wi = range_w[((size_t)s * Rn + r) * 2 + 1];
      const float v = (p == 0) ? ((q == 0) ? Wr : -Wi) : ((q == 0) ? Wi : Wr);
      const u16 h = f2bf(v);
      A1h[idx] = h;
      A1l[idx] = f2bf(v - bf2f(h));
    }
    for (int idx = gid; idx < 256 * 256; idx += gsz) {
      const int m = idx >> 8, k = idx & 255;
      const int d = m >> 1, p = m & 1, c = k >> 1, q = k & 1;
      const float Dr = dopp_w[((size_t)c * Dn + d) * 2 + 0];
      const float Di = dopp_w[((size_t)c * Dn + d) * 2 + 1];
      const float v = (p == 0) ? ((q == 0) ? Dr : -Di) : ((q == 0) ? Di : Dr);
      const u16 h = f2bf(v);
      A2h[idx] = h;
      A2l[idx] = f2bf(v - bf2f(h));
    }
    return;
  }
  // ---- tp stats1 path (1024 blocks) ----
  const int bx = blockIdx.x - 128;
  __shared__ float w1s[48];
  __shared__ float red8[8][4][2];
  const int t = threadIdx.x;
  if (t < 48) w1s[t] = w1[t];
  __syncthreads();
  float s1[8], s2[8];
#pragma unroll
  for (int o = 0; o < 8; ++o) { s1[o] = 0.f; s2[o] = 0.f; }
  for (int row = bx; row < Bn * RXn * Cn; row += 1024) {
    const float* xr = x + (size_t)row * Sn * 2;
    const float2 cc = *(const float2*)&xr[2 * t];
    const float2 mm = (t > 0) ? *(const float2*)&xr[2 * t - 2] : make_float2(0.f, 0.f);
    const float2 pp = (t < Sn - 1) ? *(const float2*)&xr[2 * t + 2] : make_float2(0.f, 0.f);
#pragma unroll
    for (int o = 0; o < 8; ++o) {
      const float* w = &w1s[o * 6];
      float h = w[0] * mm.x + w[1] * cc.x + w[2] * pp.x + w[3] * mm.y + w[4] * cc.y + w[5] * pp.y;
      s1[o] += h; s2[o] += h * h;
    }
  }
  const int lane = t & 63, wv = t >> 6;
#pragma unroll
  for (int o = 0; o < 8; ++o) {
    float v1 = s1[o], v2 = s2[o];
#pragma unroll
    for (int off = 32; off; off >>= 1) { v1 += __shfl_down(v1, off); v2 += __shfl_down(v2, off); }
    if (lane == 0) { red8[o][wv][0] = v1; red8[o][wv][1] = v2; }
  }
  __syncthreads();
  if (t < 8) {
    const float a1 = red8[t][0][0] + red8[t][1][0] + red8[t][2][0] + red8[t][3][0];
    const float a2 = red8[t][0][1] + red8[t][1][1] + red8[t][2][1] + red8[t][3][1];
    part[((size_t)t * 1024 + bx) * 2 + 0] = a1;
    part[((size_t)t * 1024 + bx) * 2 + 1] = a2;
  }
}

// Generic BN-stats finalize
__global__ __launch_bounds__(256) void k_finalize(const float* __restrict__ part, int npart,
                                                  float n, const float* __restrict__ g,
                                                  const float* __restrict__ be,
                                                  float* __restrict__ stats) {
  const int co = blockIdx.x, t = threadIdx.x;
  __shared__ float r1[256], r2[256];
  float s1 = 0.f, s2 = 0.f;
  for (int i = t; i < npart; i += 256) {
    s1 += part[((size_t)co * npart + i) * 2 + 0];
    s2 += part[((size_t)co * npart + i) * 2 + 1];
  }
  r1[t] = s1; r2[t] = s2;
  __syncthreads();
  for (int off = 128; off; off >>= 1) {
    if (t < off) { r1[t] += r1[t + off]; r2[t] += r2[t + off]; }
    __syncthreads();
  }
  if (t == 0) {
    const float mean = r1[0] / n;
    const float var  = fmaxf(r2[0] / n - mean * mean, 0.f);
    const float inv  = rsqrtf(var + 1e-5f);
    const float sc   = inv * g[co];
    stats[2 * co + 0] = sc;
    stats[2 * co + 1] = be[co] - mean * sc;
  }
}

// ============================================================================
// tp stage 2 fused: conv1 -> BN1 -> ReLU -> conv2; h2 stored packed bf16.
// 4 rows per block (amortizes dispatch ramp + weight loads; part shrinks 4x).
// ============================================================================
__global__ __launch_bounds__(256) void k_tp_fused2(const float* __restrict__ x,
                                                   const float* __restrict__ w1,
                                                   const float* __restrict__ st1,
                                                   const float* __restrict__ w2,
                                                   u32* __restrict__ h2p,
                                                   float* __restrict__ part) {
  __shared__ float a1[8][Sn + 2];
  __shared__ float w1s[48], w2s[48], st[16];
  __shared__ float red2s[2][4][2];
  const int t = threadIdx.x;
  if (t < 48) { w1s[t] = w1[t]; w2s[t] = w2[t]; }
  if (t < 16) st[t] = st1[t];
  __syncthreads();
  float s1acc[2] = {0.f, 0.f}, s2acc[2] = {0.f, 0.f};
#pragma unroll
  for (int r4 = 0; r4 < 4; ++r4) {
    const int row = blockIdx.x * 4 + r4;
    const float* xr = x + (size_t)row * Sn * 2;
    const float2 cc = *(const float2*)&xr[2 * t];
    const float2 mm = (t > 0) ? *(const float2*)&xr[2 * t - 2] : make_float2(0.f, 0.f);
    const float2 pp = (t < Sn - 1) ? *(const float2*)&xr[2 * t + 2] : make_float2(0.f, 0.f);
    if (r4) __syncthreads();   // previous row's a1 readers done before overwrite
#pragma unroll
    for (int o = 0; o < 8; ++o) {
      const float* w = &w1s[o * 6];
      float h = w[0] * mm.x + w[1] * cc.x + w[2] * pp.x + w[3] * mm.y + w[4] * cc.y + w[5] * pp.y;
      float v = fmaf(h, st[2 * o], st[2 * o + 1]);
      a1[o][1 + t] = v > 0.f ? v : 0.f;
      if (t == 0) { a1[o][0] = 0.f; a1[o][Sn + 1] = 0.f; }
    }
    __syncthreads();
    float h2v[2];
#pragma unroll
    for (int j = 0; j < 2; ++j) {
      float acc = 0.f;
#pragma unroll
      for (int o = 0; o < 8; ++o) {
        const float* w = &w2s[j * 24 + o * 3];
        acc += w[0] * a1[o][t] + w[1] * a1[o][t + 1] + w[2] * a1[o][t + 2];
      }
      h2v[j] = acc;
    }
    h2p[(size_t)row * Sn + t] = cvtpk(h2v[0], h2v[1]);
#pragma unroll
    for (int j = 0; j < 2; ++j) { s1acc[j] += h2v[j]; s2acc[j] += h2v[j] * h2v[j]; }
  }
  const int lane = t & 63, wv = t >> 6;
#pragma unroll
  for (int j = 0; j < 2; ++j) {
    float v1 = s1acc[j], v2 = s2acc[j];
#pragma unroll
    for (int off = 32; off; off >>= 1) { v1 += __shfl_down(v1, off); v2 += __shfl_down(v2, off); }
    if (lane == 0) { red2s[j][wv][0] = v1; red2s[j][wv][1] = v2; }
  }
  __syncthreads();
  if (t < 2) {
    const float a1s = red2s[t][0][0] + red2s[t][1][0] + red2s[t][2][0] + red2s[t][3][0];
    const float a2s = red2s[t][0][1] + red2s[t][1][1] + red2s[t][2][1] + red2s[t][3][1];
    part[((size_t)t * gridDim.x + blockIdx.x) * 2 + 0] = a1s;
    part[((size_t)t * gridDim.x + blockIdx.x) * 2 + 1] = a2s;
  }
}

// ============================================================================
// DFT prep: BN2+ReLU+sumRX over packed-bf16 h2 -> B1 planes bf16 hi/lo
// ============================================================================
__global__ __launch_bounds__(256) void k_prep(const u32* __restrict__ h2p,
                                              const float* __restrict__ st2,
                                              u32* __restrict__ B1h32,
                                              u32* __restrict__ B1l32) {
  const int row = blockIdx.x;
  const int s = threadIdx.x;
  const int b = row >> 7, c = row & (Cn - 1);
  const float sc0 = st2[0], sh0 = st2[1], sc1 = st2[2], sh1 = st2[3];
  float xr = 0.f, xi = 0.f;
#pragma unroll
  for (int rx = 0; rx < RXn; ++rx) {
    const u32 v = h2p[(((size_t)b * RXn + rx) * Cn + c) * Sn + s];
    const float vr = bf2f((u16)(v & 0xFFFFu));
    const float vi = bf2f((u16)(v >> 16));
    xr += fmaxf(fmaf(vr, sc0, sh0), 0.f);
    xi += fmaxf(fmaf(vi, sc1, sh1), 0.f);
  }
  u32 hi, lo;
  split2(xr, xi, hi, lo);
  B1h32[(size_t)row * 256 + s] = hi;
  B1l32[(size_t)row * 256 + s] = lo;
}

// ============================================================================
// Split-bf16 MFMA GEMM (hi/lo, ~fp32): M32 x N64 tiles, K chunk 32.
// STORE=0: rng -> B2 planes; STORE=1: dop -> rd packed bf16 {re,im} u32
// ============================================================================
template <int M, int N, int K, int STORE>
__global__ __launch_bounds__(256) void k_gemm_split(const u16* __restrict__ Ah,
                                                    const u16* __restrict__ Al,
                                                    const u16* __restrict__ Bh,
                                                    const u16* __restrict__ Bl,
                                                    u32* __restrict__ out0,
                                                    u32* __restrict__ out1) {
  __shared__ __align__(16) u16 lah[32 * 40], lal[32 * 40];
  __shared__ __align__(16) u16 lbh[64 * 40], lbl[64 * 40];
  const int tid = threadIdx.x;
  const int lane = tid & 63, wid = tid >> 6;
  const int wm = wid >> 1, wn = wid & 1;
  const int l15 = lane & 15, lg = lane >> 4;
  const int m0 = blockIdx.x * 32, n0 = blockIdx.y * 64;
  f32x4 acc[2];
  acc[0] = (f32x4){0.f, 0.f, 0.f, 0.f};
  acc[1] = (f32x4){0.f, 0.f, 0.f, 0.f};
  const int arow = tid >> 3, ak = (tid & 7) * 4;
  const int brow = tid >> 2, bk = (tid & 3) * 8;
  for (int k0 = 0; k0 < K; k0 += 32) {
    *(u16x4*)&lah[arow * 40 + ak] = *(const u16x4*)&Ah[(size_t)(m0 + arow) * K + k0 + ak];
    *(u16x4*)&lal[arow * 40 + ak] = *(const u16x4*)&Al[(size_t)(m0 + arow) * K + k0 + ak];
    *(u16x8*)&lbh[brow * 40 + bk] = *(const u16x8*)&Bh[(size_t)(n0 + brow) * K + k0 + bk];
    *(u16x8*)&lbl[brow * 40 + bk] = *(const u16x8*)&Bl[(size_t)(n0 + brow) * K + k0 + bk];
    __syncthreads();
    const bf16x8 ah = *(const bf16x8*)&lah[(wm * 16 + l15) * 40 + lg * 8];
    const bf16x8 al = *(const bf16x8*)&lal[(wm * 16 + l15) * 40 + lg * 8];
#pragma unroll
    for (int f = 0; f < 2; ++f) {
      const bf16x8 bh = *(const bf16x8*)&lbh[(wn * 32 + f * 16 + l15) * 40 + lg * 8];
      const bf16x8 bl = *(const bf16x8*)&lbl[(wn * 32 + f * 16 + l15) * 40 + lg * 8];
      acc[f] = __builtin_amdgcn_mfma_f32_16x16x32_bf16(ah, bh, acc[f], 0, 0, 0);
      acc[f] = __builtin_amdgcn_mfma_f32_16x16x32_bf16(ah, bl, acc[f], 0, 0, 0);
      acc[f] = __builtin_amdgcn_mfma_f32_16x16x32_bf16(al, bh, acc[f], 0, 0, 0);
    }
    __syncthreads();
  }
  const int mb = m0 + wm * 16 + lg * 4;
#pragma unroll
  for (int f = 0; f < 2; ++f) {
    const int n = n0 + wn * 32 + f * 16 + l15;
    if (STORE == 0) {
      const int b = n >> 7, c = n & 127;
#pragma unroll
      for (int pair = 0; pair < 2; ++pair) {
        const int r = (mb >> 1) + pair;
        u32 hi, lo;
        split2(acc[f][2 * pair], acc[f][2 * pair + 1], hi, lo);
        const size_t idx = ((size_t)b * 256 + r) * 128 + c;
        out0[idx] = hi;
        out1[idx] = lo;
      }
    } else {
      const int b = n >> 8, r = n & 255;
#pragma unroll
      for (int pair = 0; pair < 2; ++pair) {
        const int d = (mb >> 1) + pair;
        out0[((size_t)b * 128 + d) * 256 + r] = cvtpk(acc[f][2 * pair], acc[f][2 * pair + 1]);
      }
    }
  }
}

// ============================================================================
// MFMA implicit-GEMM 3x3 conv (pad 1), NHWC bf16 activations (raw), fused:
//   MODE 1: bnrelu(in)                            (dec3)
//   MODE 2: bnrelu(2x2 maxpool of raw)            (enc2, enc3)
//   MODE 3: up2(bnrelu(in @ H/2 x W/2)) + bnrelu(in2 @ H x W)  (dec2, dec1)
// MODE 3: two-phase in-LDS dedup. Phase A computes bnrelu(in_lowres) ONCE
// per low-res pixel of the block's support region into f32 LDS. Phase B
// lerps from LDS + adds skip. Bit-identical math.
// ============================================================================
template <int CIN, int COUT, int H, int W, int TH, int TW, int MW, int NW,
          int WAVES_M, int WAVES_N, int MODE>
__global__ __launch_bounds__(256) void k_conv_mfma(const u16* __restrict__ in,
                                                   const u16* __restrict__ wpk,
                                                   const float* __restrict__ in_stats,
                                                   const u16* __restrict__ in2,
                                                   const float* __restrict__ in2_stats,
                                                   u16* __restrict__ out,
                                                   float* __restrict__ part) {
  constexpr int COG = WAVES_M * MW * 16;
  constexpr int CHUNKS = CIN / 32;
  constexpr int NFROW = TW / 16;
  constexpr int XROWS = TH + 2, XCOLS = TW + 2;
  // MODE 3 support region (TH=8, TW=32, scale ~0.5): rows <= 7, cols <= 19
  constexpr int RR = 7, RC = 19;
  static_assert(WAVES_M * WAVES_N == 4, "waves");
  static_assert(WAVES_N * NW * 16 == TH * TW, "pixel cover");
  static_assert(MODE != 3 || (TH == 8 && TW == 32), "region sized for 8x32");
  __shared__ __align__(16) u16 xs[XROWS * XCOLS * 40];
  __shared__ float red1[WAVES_N][COG], red2[WAVES_N][COG];
  __shared__ __align__(16) float sst1[2 * CIN];
  __shared__ __align__(16) float sst2[(MODE == 3) ? 2 * CIN : 4];
  __shared__ __align__(16) float reg_lds[(MODE == 3) ? RR * RC * 32 : 4];
  const int tid = threadIdx.x;
  const int lane = tid & 63;
  const int wid = tid >> 6;
  const int wave_m = wid / WAVES_N;
  const int wave_n = wid % WAVES_N;
  const int l15 = lane & 15, lg = lane >> 4;
  constexpr int TILES_W = W / TW;
  const int tile = blockIdx.x;
  const int tw = tile % TILES_W, th = tile / TILES_W;
  const int h0 = th * TH, w0 = tw * TW;
  const int cog = blockIdx.y, b = blockIdx.z;
  // preload BN stats into LDS (one barrier; bit-identical copy)
  for (int i = tid; i < 2 * CIN; i += 256) sst1[i] = in_stats[i];
  if (MODE == 3)
    for (int i = tid; i < 2 * CIN; i += 256) sst2[i] = in2_stats[i];
  __syncthreads();
  f32x4 acc[MW][NW];
#pragma unroll
  for (int m = 0; m < MW; ++m)
#pragma unroll
    for (int f = 0; f < NW; ++f) acc[m][f] = (f32x4){0.f, 0.f, 0.f, 0.f};

  for (int q = 0; q < CHUNKS; ++q) {
    // ---- hoisted BN stats (thread-invariant within the item loops) ----
    const int ci0 = (tid & 3) * 8;
    const int cch = q * 32 + ci0;
    float sc[8], sh[8];
#pragma unroll
    for (int k = 0; k < 4; ++k) {
      const float4 qq = *(const float4*)&sst1[2 * cch + 4 * k];
      sc[2 * k] = qq.x; sh[2 * k] = qq.y; sc[2 * k + 1] = qq.z; sh[2 * k + 1] = qq.w;
    }
    float ec[8], es[8];
    if constexpr (MODE == 3) {
#pragma unroll
      for (int k = 0; k < 4; ++k) {
        const float4 qq = *(const float4*)&sst2[2 * cch + 4 * k];
        ec[2 * k] = qq.x; es[2 * k] = qq.y; ec[2 * k + 1] = qq.z; es[2 * k + 1] = qq.w;
      }
    }
    if constexpr (MODE == 3) {
      constexpr int Hi2 = H / 2, Wi2 = W / 2;
      constexpr float steph = (float)(Hi2 - 1) / (float)(H - 1);
      constexpr float stepw = (float)(Wi2 - 1) / (float)(W - 1);
      const int gh_min = (h0 - 1 > 0) ? h0 - 1 : 0;
      const int gw_min = (w0 - 1 > 0) ? w0 - 1 : 0;
      const int lo0 = (int)((float)gh_min * steph);
      const int lw0 = (int)((float)gw_min * stepw);
      // ---- phase A: bnrelu(low-res) once per region pixel -> f32 LDS ----
      for (int i = tid; i < RR * RC * 4; i += 256) {
        const int pixr = i >> 2;
        const int rcc = pixr % RC;
        const int rrr = pixr / RC;
        const int lr = (lo0 + rrr < Hi2 - 1) ? lo0 + rrr : Hi2 - 1;
        const int lc = (lw0 + rcc < Wi2 - 1) ? lw0 + rcc : Wi2 - 1;
        float tv[8];
        ld8bf(&in[(((size_t)b * Hi2 + lr) * Wi2 + lc) * CIN + cch], tv);
#pragma unroll
        for (int k = 0; k < 8; ++k) tv[k] = fmaxf(fmaf(tv[k], sc[k], sh[k]), 0.f);
        *(float4*)&reg_lds[(rrr * RC + rcc) * 32 + ci0] = *(float4*)&tv[0];
        *(float4*)&reg_lds[(rrr * RC + rcc) * 32 + ci0 + 4] = *(float4*)&tv[4];
      }
      __syncthreads();
      // ---- phase B: lerp from LDS + skip bnrelu -> xs ----
      for (int i = tid; i < XROWS * XCOLS * 4; i += 256) {
        const int pix = i >> 2;
        const int col = pix % XCOLS;
        const int row = pix / XCOLS;
        const int gh = h0 + row - 1, gw = w0 + col - 1;
        u32x4 enc = (u32x4){0u, 0u, 0u, 0u};
        if (gh >= 0 && gh < H && gw >= 0 && gw < W) {
          const float ph = (float)gh * steph;
          const int hlo = (int)ph;
          const float fh = ph - (float)hlo;
          const int hhi = (hlo + 1 < Hi2) ? hlo + 1 : Hi2 - 1;
          const float pw = (float)gw * stepw;
          const int wl = (int)pw;
          const float fw = pw - (float)wl;
          const int wh = (wl + 1 < Wi2) ? wl + 1 : Wi2 - 1;
          const float w00 = (1.f - fh) * (1.f - fw), w01 = (1.f - fh) * fw;
          const float w10 = fh * (1.f - fw), w11 = fh * fw;
          const float* p00 = &reg_lds[((hlo - lo0) * RC + (wl - lw0)) * 32 + ci0];
          const float* p01 = &reg_lds[((hlo - lo0) * RC + (wh - lw0)) * 32 + ci0];
          const float* p10 = &reg_lds[((hhi - lo0) * RC + (wl - lw0)) * 32 + ci0];
          const float* p11 = &reg_lds[((hhi - lo0) * RC + (wh - lw0)) * 32 + ci0];
          float ev[8];
          ld8bf(&in2[(((size_t)b * H + gh) * W + gw) * CIN + cch], ev);
          float vv[8];
#pragma unroll
          for (int k = 0; k < 8; ++k) {
            vv[k] = w00 * p00[k] + w01 * p01[k] + w10 * p10[k] + w11 * p11[k]
                  + fmaxf(fmaf(ev[k], ec[k], es[k]), 0.f);
          }
#pragma unroll
          for (int j = 0; j < 4; ++j) enc[j] = cvtpk(vv[2 * j], vv[2 * j + 1]);
        }
        *(u32x4*)&xs[(row * XCOLS + col) * 40 + ci0] = enc;
      }
    } else {
      for (int i = tid; i < XROWS * XCOLS * 4; i += 256) {
        const int pix = i >> 2;
        const int col = pix % XCOLS;
        const int row = pix / XCOLS;
        const int gh = h0 + row - 1, gw = w0 + col - 1;
        u32x4 enc = (u32x4){0u, 0u, 0u, 0u};
        if (gh >= 0 && gh < H && gw >= 0 && gw < W) {
          float vv[8];
          if constexpr (MODE == 1) {
            float tv[8];
            ld8bf(&in[(((size_t)b * H + gh) * W + gw) * CIN + cch], tv);
#pragma unroll
            for (int k = 0; k < 8; ++k) vv[k] = fmaxf(fmaf(tv[k], sc[k], sh[k]), 0.f);
          } else {
            // MODE 2: max of raw taps first, then single BN+ReLU (sc > 0)
            const size_t rs = (size_t)(2 * W) * CIN;
            const u16* pb = &in[(((size_t)b * 2 * H + 2 * gh) * (2 * W) + 2 * gw) * CIN + cch];
            float tp[4][8];
            ld8bf(pb, tp[0]);
            ld8bf(pb + CIN, tp[1]);
            ld8bf(pb + rs, tp[2]);
            ld8bf(pb + rs + CIN, tp[3]);
#pragma unroll
            for (int k = 0; k < 8; ++k) {
              const float mx = fmaxf(fmaxf(tp[0][k], tp[1][k]), fmaxf(tp[2][k], tp[3][k]));
              vv[k] = fmaxf(fmaf(mx, sc[k], sh[k]), 0.f);
            }
          }
#pragma unroll
          for (int j = 0; j < 4; ++j) enc[j] = cvtpk(vv[2 * j], vv[2 * j + 1]);
        }
        *(u32x4*)&xs[(row * XCOLS + col) * 40 + ci0] = enc;
      }
    }
    __syncthreads();
#pragma unroll
    for (int t = 0; t < 9; ++t) {
      const int ky = t / 3, kx = t % 3;
      bf16x8 afr[MW];
#pragma unroll
      for (int m = 0; m < MW; ++m) {
        const int mfg = cog * (COG / 16) + wave_m * MW + m;
        afr[m] = *(const bf16x8*)&wpk[((((size_t)mfg * CHUNKS + q) * 9 + t) * 64 + lane) * 8];
      }
      bf16x8 bfr[NW];
#pragma unroll
      for (int f = 0; f < NW; ++f) {
        const int nf = wave_n * NW + f;
        const int r = nf / NFROW;
        const int cseg = (nf % NFROW) * 16;
        bfr[f] = *(const bf16x8*)&xs[((r + ky) * XCOLS + (cseg + l15 + kx)) * 40 + lg * 8];
      }
#pragma unroll
      for (int m = 0; m < MW; ++m)
#pragma unroll
        for (int f = 0; f < NW; ++f)
          acc[m][f] = __builtin_amdgcn_mfma_f32_16x16x32_bf16(afr[m], bfr[f], acc[m][f], 0, 0, 0);
    }
    __syncthreads();
  }

#pragma unroll
  for (int m = 0; m < MW; ++m) {
    const int cobase = cog * COG + (wave_m * MW + m) * 16 + lg * 4;
#pragma unroll
    for (int f = 0; f < NW; ++f) {
      const int nf = wave_n * NW + f;
      const int r = nf / NFROW;
      const int cseg = (nf % NFROW) * 16;
      u16* op = out + (((size_t)b * H + h0 + r) * W + (w0 + cseg + l15)) * COUT + cobase;
      u32x2 ov;
      ov[0] = cvtpk(acc[m][f][0], acc[m][f][1]);
      ov[1] = cvtpk(acc[m][f][2], acc[m][f][3]);
      *(u32x2*)op = ov;
    }
  }
#pragma unroll
  for (int m = 0; m < MW; ++m)
#pragma unroll
    for (int reg = 0; reg < 4; ++reg) {
      float s1 = 0.f, s2 = 0.f;
#pragma unroll
      for (int f = 0; f < NW; ++f) { const float v = acc[m][f][reg]; s1 += v; s2 += v * v; }
#pragma unroll
      for (int off = 1; off < 16; off <<= 1) { s1 += __shfl_xor(s1, off); s2 += __shfl_xor(s2, off); }
      if (l15 == 0) {
        const int ch = (wave_m * MW + m) * 16 + lg * 4 + reg;
        red1[wave_n][ch] = s1; red2[wave_n][ch] = s2;
      }
    }
  __syncthreads();
  if (tid < COG) {
    float s1 = 0.f, s2 = 0.f;
#pragma unroll
    for (int wn = 0; wn < WAVES_N; ++wn) { s1 += red1[wn][tid]; s2 += red2[wn][tid]; }
    const int npart = gridDim.x * gridDim.z;
    const int pidx = blockIdx.z * gridDim.x + blockIdx.x;
    part[((size_t)(cog * COG + tid) * npart + pidx) * 2 + 0] = s1;
    part[((size_t)(cog * COG + tid) * npart + pidx) * 2 + 1] = s2;
  }
}

// ============================================================================
// enc1 direct fp32 conv: packed-bf16 rd in (C=2) -> NHWC out (C=32 bf16)
// ============================================================================
__global__ __launch_bounds__(256) void k_conv1(const u32* __restrict__ in,
                                               const float* __restrict__ wgt,
                                               u16* __restrict__ out,
                                               float* __restrict__ part) {
  constexpr int H = 128, W = 256, TW = 64, TH = 16, COG = 16, COUT = 32;
  const int tid = threadIdx.x;
  const int tile = blockIdx.x;
  const int tw = tile & 3, th = tile >> 2;
  const int cog = blockIdx.y, b = blockIdx.z;
  const int ty = tid >> 4;
  const int wofs = (tid & 15) * 4;
  const int h0 = th * TH, w0t = tw * TW;
  __shared__ float xs0[TH + 2][TW + 3], xs1[TH + 2][TW + 3];
  __shared__ float ws[2][COG][12];
  __shared__ float redp[4][COG], redq[4][COG];
  for (int i = tid; i < 2 * COG * 9; i += 256) {
    const int tap = i % 9, rest = i / 9;
    const int ci = rest & 1, co = rest >> 1;
    ws[ci][co][tap] = wgt[((size_t)(cog * COG + co) * 2 + ci) * 9 + tap];
  }
  for (int i = tid; i < (TH + 2) * (TW + 2); i += 256) {
    const int col = i % (TW + 2), row = i / (TW + 2);
    const int gh = h0 + row - 1, gw = w0t + col - 1;
    float v0 = 0.f, v1 = 0.f;
    if (gh >= 0 && gh < H && gw >= 0 && gw < W) {
      const u32 v = in[((size_t)b * H + gh) * W + gw];
      v0 = bf2f((u16)(v & 0xFFFFu));
      v1 = bf2f((u16)(v >> 16));
    }
    xs0[row][col] = v0; xs1[row][col] = v1;
  }
  __syncthreads();
  float acc[4][COG];
#pragma unroll
  for (int px = 0; px < 4; ++px)
#pragma unroll
    for (int co = 0; co < COG; ++co) acc[px][co] = 0.f;
#pragma unroll
  for (int ci = 0; ci < 2; ++ci) {
    float xrow[3][6];
#pragma unroll
    for (int ky = 0; ky < 3; ++ky)
#pragma unroll
      for (int j = 0; j < 6; ++j)
        xrow[ky][j] = ci ? xs1[ty + ky][wofs + j] : xs0[ty + ky][wofs + j];
#pragma unroll
    for (int co = 0; co < COG; ++co) {
      const float4 wq0 = *(const float4*)&ws[ci][co][0];
      const float4 wq1 = *(const float4*)&ws[ci][co][4];
      const float  w8 = ws[ci][co][8];
      const float wv[9] = {wq0.x, wq0.y, wq0.z, wq0.w, wq1.x, wq1.y, wq1.z, wq1.w, w8};
#pragma unroll
      for (int ky = 0; ky < 3; ++ky)
#pragma unroll
        for (int kx = 0; kx < 3; ++kx)
#pragma unroll
          for (int px = 0; px < 4; ++px)
            acc[px][co] = fmaf(xrow[ky][px + kx], wv[ky * 3 + kx], acc[px][co]);
    }
  }
#pragma unroll
  for (int px = 0; px < 4; ++px) {
    u16* op = out + (((size_t)b * H + h0 + ty) * W + (w0t + wofs + px)) * COUT + cog * COG;
    u32x4 ov;
    ov[0] = cvtpk(acc[px][0], acc[px][1]);
    ov[1] = cvtpk(acc[px][2], acc[px][3]);
    ov[2] = cvtpk(acc[px][4], acc[px][5]);
    ov[3] = cvtpk(acc[px][6], acc[px][7]);
    *(u32x4*)&op[0] = ov;
    u32x4 ov2;
    ov2[0] = cvtpk(acc[px][8], acc[px][9]);
    ov2[1] = cvtpk(acc[px][10], acc[px][11]);
    ov2[2] = cvtpk(acc[px][12], acc[px][13]);
    ov2[3] = cvtpk(acc[px][14], acc[px][15]);
    *(u32x4*)&op[8] = ov2;
  }
  const int lane = tid & 63, wid = tid >> 6;
#pragma unroll
  for (int co = 0; co < COG; ++co) {
    float v1 = 0.f, v2 = 0.f;
#pragma unroll
    for (int px = 0; px < 4; ++px) { v1 += acc[px][co]; v2 += acc[px][co] * acc[px][co]; }
#pragma unroll
    for (int off = 32; off; off >>= 1) { v1 += __shfl_down(v1, off); v2 += __shfl_down(v2, off); }
    if (lane == 0) { redp[wid][co] = v1; redq[wid][co] = v2; }
  }
  __syncthreads();
  if (tid < COG) {
    const int npart = gridDim.x * gridDim.z;
    const int pidx = blockIdx.z * gridDim.x + blockIdx.x;
    part[((size_t)(cog * COG + tid) * npart + pidx) * 2 + 0] = redp[0][tid] + redp[1][tid] + redp[2][tid] + redp[3][tid];
    part[((size_t)(cog * COG + tid) * npart + pidx) * 2 + 1] = redq[0][tid] + redq[1][tid] + redq[2][tid] + redq[3][tid];
  }
}

// final: bnrelu(d1 bf16) -> 1x1 conv (16->1) + bias + sigmoid
__global__ __launch_bounds__(256) void k_out_bn(const u16* __restrict__ d1,
                                                const float* __restrict__ st,
                                                const float* __restrict__ ow,
                                                const float* __restrict__ ob,
                                                float* __restrict__ out) {
  const size_t i = (size_t)blockIdx.x * 256 + threadIdx.x;
  const size_t total = (size_t)Bn * Dn * Rn;
  if (i >= total) return;
  const u16* p = d1 + i * 16;
  float v[16];
  ld8bf(p, v);
  ld8bf(p + 8, v + 8);
  float acc = ob[0];
#pragma unroll
  for (int k = 0; k < 16; ++k) {
    const float2 q = *(const float2*)&st[2 * k];
    acc += fmaxf(fmaf(v[k], q.x, q.y), 0.f) * ow[k];
  }
  out[i] = 1.f / (1.f + expf(-acc));
}

// ============================================================================
extern "C" void kernel_launch(void* const* d_in, const int* in_sizes, int n_in,
                              void* d_out, int out_size, void* d_ws, size_t ws_size,
                              hipStream_t stream) {
  (void)in_sizes; (void)n_in; (void)out_size; (void)ws_size;
  const float* x       = (const float*)d_in[0];
  const float* tp_w1   = (const float*)d_in[1];
  const float* tp_g1   = (const float*)d_in[3];
  const float* tp_be1  = (const float*)d_in[4];
  const float* tp_w2   = (const float*)d_in[5];
  const float* tp_g2   = (const float*)d_in[7];
  const float* tp_be2  = (const float*)d_in[8];
  const float* range_w = (const float*)d_in[9];
  const float* dopp_w  = (const float*)d_in[10];
  const float* e1w = (const float*)d_in[11]; const float* e1g = (const float*)d_in[13]; const float* e1b = (const float*)d_in[14];
  const float* e2w = (const float*)d_in[15]; const float* e2g = (const float*)d_in[17]; const float* e2b = (const float*)d_in[18];
  const float* e3w = (const float*)d_in[19]; const float* e3g = (const float*)d_in[21]; const float* e3b = (const float*)d_in[22];
  const float* d3w = (const float*)d_in[23]; const float* d3g = (const float*)d_in[25]; const float* d3b = (const float*)d_in[26];
  const float* d2w = (const float*)d_in[27]; const float* d2g = (const float*)d_in[29]; const float* d2b = (const float*)d_in[30];
  const float* d1w = (const float*)d_in[31]; const float* d1g = (const float*)d_in[33]; const float* d1b = (const float*)d_in[34];
  const float* out_w = (const float*)d_in[35];
  const float* out_b = (const float*)d_in[36];
  float* outp = (float*)d_out;

  // -------- workspace arena; U-Net raw tensors bf16 NHWC --------
  float* W  = (float*)d_ws;
  u16* Ae1  = (u16*)W;
  float* Bx = W + 16777216;
  u16* Ce2  = (u16*)(W + 33554432);
  u16* Ee3  = (u16*)(W + 41943040);
  u16* Fd3  = (u16*)(W + 46137344);
  float* part  = W + 48234496;
  float* stats = part + 262144;
  u16* wpk_e2 = (u16*)(stats + 1024);
  u16* wpk_e3 = wpk_e2 + 18432;
  u16* wpk_d3 = wpk_e3 + 73728;
  u16* wpk_d2 = wpk_d3 + 73728;
  u16* wpk_d1 = wpk_d2 + 18432;
  u16* A1h = wpk_d1 + 4608;
  u16* A1l = A1h + 262144;
  u16* A2h = A1l + 262144;
  u16* A2l = A2h + 65536;
  u16* B1h = A2l + 65536;
  u16* B1l = B1h + 1048576;
  u16* B2h = B1l + 1048576;
  u16* B2l = B2h + 1048576;

  u32* h2p = (u32*)Bx;                         // [8192][256] packed bf16 pairs (8MB)
  u32* rd  = (u32*)(Bx + 2097152 + 65536);     // [b][128][256] packed {re,im} (2MB)
  u16* d1  = (u16*)Bx;                         // [b][128][256][16] bf16 (h2p/rd dead)

  float* st_tp1 = stats;
  float* st_tp2 = stats + 16;
  float* st_e1  = stats + 32;
  float* st_e2  = stats + 96;
  float* st_e3  = stats + 224;
  float* st_d3  = stats + 480;
  float* st_d2  = stats + 608;
  float* st_d1  = stats + 672;

  const float Ntp = 2097152.f;

  // ---- merged head: weight packing (blocks 0-127) || tp stats1 (128-1151) ----
  k_pack_stats<<<1152, 256, 0, stream>>>(e2w, e3w, d3w, d2w, d1w, range_w, dopp_w,
                                         wpk_e2, wpk_e3, wpk_d3, wpk_d2, wpk_d1,
                                         A1h, A1l, A2h, A2l,
                                         x, tp_w1, part);
  k_finalize<<<8, 256, 0, stream>>>(part, 1024, Ntp, tp_g1, tp_be1, st_tp1);
  k_tp_fused2<<<Bn * RXn * Cn / 4, 256, 0, stream>>>(x, tp_w1, st_tp1, tp_w2, h2p, part);
  k_finalize<<<2, 256, 0, stream>>>(part, Bn * RXn * Cn / 4, Ntp, tp_g2, tp_be2, st_tp2);

  // ---- DFTs via split-bf16 MFMA GEMMs ----
  k_prep<<<Bn * Cn, 256, 0, stream>>>(h2p, st_tp2, (u32*)B1h, (u32*)B1l);
  k_gemm_split<512, 2048, 512, 0><<<dim3(16, 32), 256, 0, stream>>>(
      A1h, A1l, B1h, B1l, (u32*)B2h, (u32*)B2l);
  k_gemm_split<256, 4096, 256, 1><<<dim3(8, 64), 256, 0, stream>>>(
      A2h, A2l, B2h, B2l, rd, nullptr);

  // ---- U-Net ----
  k_conv1<<<dim3(32, 2, Bn), 256, 0, stream>>>(rd, e1w, Ae1, part);
  k_finalize<<<32, 256, 0, stream>>>(part, 512, 524288.f, e1g, e1b, st_e1);
  k_conv_mfma<32, 64, 64, 128, 8, 32, 2, 8, 2, 2, 2><<<dim3(32, 1, Bn), 256, 0, stream>>>(
      Ae1, wpk_e2, st_e1, nullptr, nullptr, Ce2, part);
  k_finalize<<<64, 256, 0, stream>>>(part, 512, 131072.f, e2g, e2b, st_e2);
  k_conv_mfma<64, 128, 32, 64, 4, 16, 1, 4, 4, 1, 2><<<dim3(32, 2, Bn), 256, 0, stream>>>(
      Ce2, wpk_e3, st_e2, nullptr, nullptr, Ee3, part);
  k_finalize<<<128, 256, 0, stream>>>(part, 512, 32768.f, e3g, e3b, st_e3);
  k_conv_mfma<128, 64, 32, 64, 4, 16, 1, 4, 4, 1, 1><<<dim3(32, 1, Bn), 256, 0, stream>>>(
      Ee3, wpk_d3, st_e3, nullptr, nullptr, Fd3, part);
  k_finalize<<<64, 256, 0, stream>>>(part, 512, 32768.f, d3g, d3b, st_d3);
  k_conv_mfma<64, 32, 64, 128, 8, 32, 1, 8, 2, 2, 3><<<dim3(32, 1, Bn), 256, 0, stream>>>(
      Fd3, wpk_d2, st_d3, Ce2, st_e2, Ee3, part);
  k_finalize<<<32, 256, 0, stream>>>(part, 512, 131072.f, d2g, d2b, st_d2);
  k_conv_mfma<32, 16, 128, 256, 8, 32, 1, 4, 1, 4, 3><<<dim3(128, 1, Bn), 256, 0, stream>>>(
      Ee3, wpk_d1, st_d2, Ae1, st_e1, d1, part);
  k_finalize<<<16, 256, 0, stream>>>(part, 2048, 524288.f, d1g, d1b, st_d1);
  k_out_bn<<<2048, 256, 0, stream>>>(d1, st_d1, out_w, out_b, outp);
}

// Round 9
// 209.981 us; speedup vs baseline: 6.8480x; 1.0067x over previous
//
#include <hip/hip_runtime.h>
#include <cmath>

constexpr int Bn = 16, RXn = 4, Cn = 128, Sn = 256, Dn = 128, Rn = 256;

typedef __attribute__((ext_vector_type(8))) short bf16x8;
typedef __attribute__((ext_vector_type(4))) float f32x4;
typedef unsigned short u16;
typedef unsigned int u32;
typedef __attribute__((ext_vector_type(4))) u16 u16x4;
typedef __attribute__((ext_vector_type(8))) u16 u16x8;
typedef __attribute__((ext_vector_type(2))) u32 u32x2;
typedef __attribute__((ext_vector_type(4))) u32 u32x4;

__device__ __forceinline__ u16 f2bf(float f) {
  union { float f; u32 u; } v; v.f = f;
  const u32 r = v.u + 0x7FFFu + ((v.u >> 16) & 1u);
  return (u16)(r >> 16);
}
__device__ __forceinline__ float bf2f(u16 h) {
  union { u32 u; float f; } v; v.u = (u32)h << 16; return v.f;
}
// HW pack-convert: lo -> bits[15:0], hi -> bits[31:16], RNE
__device__ __forceinline__ u32 cvtpk(float lo, float hi) {
  u32 r;
  asm("v_cvt_pk_bf16_f32 %0, %1, %2" : "=v"(r) : "v"(lo), "v"(hi));
  return r;
}
__device__ __forceinline__ void split2(float a, float b, u32& hi, u32& lo) {
  hi = cvtpk(a, b);
  union { u32 u; float f; } va, vb;
  va.u = hi << 16;
  vb.u = hi & 0xFFFF0000u;
  lo = cvtpk(a - va.f, b - vb.f);
}
__device__ __forceinline__ void ld8bf(const u16* __restrict__ p, float* v) {
  const u16x8 h = *(const u16x8*)p;
#pragma unroll
  for (int k = 0; k < 8; ++k) v[k] = bf2f(h[k]);
}

// ============================================================================
// Weight packing helper
// ============================================================================
__device__ __forceinline__ void pack_seg(const float* __restrict__ w, u16* __restrict__ wpk,
                                         int CIN, int COUT, int gid, int gsz) {
  const int total = COUT * CIN * 9;
  const int chunks = CIN >> 5;
  for (int idx = gid; idx < total; idx += gsz) {
    const int j = idx & 7;
    const int l = (idx >> 3) & 63;
    const int rest = idx >> 9;
    const int t = rest % 9;
    const int rest2 = rest / 9;
    const int q = rest2 % chunks;
    const int mf = rest2 / chunks;
    const int co = mf * 16 + (l & 15);
    const int ci = q * 32 + ((l >> 4) << 3) + j;
    wpk[idx] = f2bf(w[((size_t)co * CIN + ci) * 9 + t]);
  }
}

// ============================================================================
// Merged head kernel: blocks 0..127 = weight/DFT packing (independent of x);
// blocks 128..1151 = tp stats stage 1 (reads x). Disjoint in/out, no sync.
// ============================================================================
__global__ __launch_bounds__(256) void k_pack_stats(
    const float* __restrict__ e2w, const float* __restrict__ e3w,
    const float* __restrict__ d3w, const float* __restrict__ d2w,
    const float* __restrict__ d1w,
    const float* __restrict__ range_w, const float* __restrict__ dopp_w,
    u16* __restrict__ p_e2, u16* __restrict__ p_e3,
    u16* __restrict__ p_d3, u16* __restrict__ p_d2,
    u16* __restrict__ p_d1,
    u16* __restrict__ A1h, u16* __restrict__ A1l,
    u16* __restrict__ A2h, u16* __restrict__ A2l,
    const float* __restrict__ x, const float* __restrict__ w1,
    float* __restrict__ part) {
  if (blockIdx.x < 128) {
    // ---- packing path ----
    const int gid = blockIdx.x * 256 + threadIdx.x;
    const int gsz = 128 * 256;
    pack_seg(e2w, p_e2, 32, 64, gid, gsz);
    pack_seg(e3w, p_e3, 64, 128, gid, gsz);
    pack_seg(d3w, p_d3, 128, 64, gid, gsz);
    pack_seg(d2w, p_d2, 64, 32, gid, gsz);
    pack_seg(d1w, p_d1, 32, 16, gid, gsz);
    for (int idx = gid; idx < 512 * 512; idx += gsz) {
      const int m = idx >> 9, k = idx & 511;
      const int r = m >> 1, p = m & 1, s = k >> 1, q = k & 1;
      const float Wr = range_w[((size_t)s * Rn + r) * 2 + 0];
      const float Wi = range_w[((size_t)s * Rn + r) * 2 + 1];
      const float v = (p == 0) ? ((q == 0) ? Wr : -Wi) : ((q == 0) ? Wi : Wr);
      const u16 h = f2bf(v);
      A1h[idx] = h;
      A1l[idx] = f2bf(v - bf2f(h));
    }
    for (int idx = gid; idx < 256 * 256; idx += gsz) {
      const int m = idx >> 8, k = idx & 255;
      const int d = m >> 1, p = m & 1, c = k >> 1, q = k & 1;
      const float Dr = dopp_w[((size_t)c * Dn + d) * 2 + 0];
      const float Di = dopp_w[((size_t)c * Dn + d) * 2 + 1];
      const float v = (p == 0) ? ((q == 0) ? Dr : -Di) : ((q == 0) ? Di : Dr);
      const u16 h = f2bf(v);
      A2h[idx] = h;
      A2l[idx] = f2bf(v - bf2f(h));
    }
    return;
  }
  // ---- tp stats1 path (1024 blocks) ----
  const int bx = blockIdx.x - 128;
  __shared__ float w1s[48];
  __shared__ float red8[8][4][2];
  const int t = threadIdx.x;
  if (t < 48) w1s[t] = w1[t];
  __syncthreads();
  float s1[8], s2[8];
#pragma unroll
  for (int o = 0; o < 8; ++o) { s1[o] = 0.f; s2[o] = 0.f; }
  for (int row = bx; row < Bn * RXn * Cn; row += 1024) {
    const float* xr = x + (size_t)row * Sn * 2;
    const float2 cc = *(const float2*)&xr[2 * t];
    const float2 mm = (t > 0) ? *(const float2*)&xr[2 * t - 2] : make_float2(0.f, 0.f);
    const float2 pp = (t < Sn - 1) ? *(const float2*)&xr[2 * t + 2] : make_float2(0.f, 0.f);
#pragma unroll
    for (int o = 0; o < 8; ++o) {
      const float* w = &w1s[o * 6];
      float h = w[0] * mm.x + w[1] * cc.x + w[2] * pp.x + w[3] * mm.y + w[4] * cc.y + w[5] * pp.y;
      s1[o] += h; s2[o] += h * h;
    }
  }
  const int lane = t & 63, wv = t >> 6;
#pragma unroll
  for (int o = 0; o < 8; ++o) {
    float v1 = s1[o], v2 = s2[o];
#pragma unroll
    for (int off = 32; off; off >>= 1) { v1 += __shfl_down(v1, off); v2 += __shfl_down(v2, off); }
    if (lane == 0) { red8[o][wv][0] = v1; red8[o][wv][1] = v2; }
  }
  __syncthreads();
  if (t < 8) {
    const float a1 = red8[t][0][0] + red8[t][1][0] + red8[t][2][0] + red8[t][3][0];
    const float a2 = red8[t][0][1] + red8[t][1][1] + red8[t][2][1] + red8[t][3][1];
    part[((size_t)t * 1024 + bx) * 2 + 0] = a1;
    part[((size_t)t * 1024 + bx) * 2 + 1] = a2;
  }
}

// Generic BN-stats finalize
__global__ __launch_bounds__(256) void k_finalize(const float* __restrict__ part, int npart,
                                                  float n, const float* __restrict__ g,
                                                  const float* __restrict__ be,
                                                  float* __restrict__ stats) {
  const int co = blockIdx.x, t = threadIdx.x;
  __shared__ float r1[256], r2[256];
  float s1 = 0.f, s2 = 0.f;
  for (int i = t; i < npart; i += 256) {
    s1 += part[((size_t)co * npart + i) * 2 + 0];
    s2 += part[((size_t)co * npart + i) * 2 + 1];
  }
  r1[t] = s1; r2[t] = s2;
  __syncthreads();
  for (int off = 128; off; off >>= 1) {
    if (t < off) { r1[t] += r1[t + off]; r2[t] += r2[t + off]; }
    __syncthreads();
  }
  if (t == 0) {
    const float mean = r1[0] / n;
    const float var  = fmaxf(r2[0] / n - mean * mean, 0.f);
    const float inv  = rsqrtf(var + 1e-5f);
    const float sc   = inv * g[co];
    stats[2 * co + 0] = sc;
    stats[2 * co + 1] = be[co] - mean * sc;
  }
}

// ============================================================================
// tp stage 2 fused: conv1 -> BN1 -> ReLU -> conv2; h2 stored packed bf16.
// 4 rows per block (amortizes dispatch ramp + weight loads; part shrinks 4x).
// ============================================================================
__global__ __launch_bounds__(256) void k_tp_fused2(const float* __restrict__ x,
                                                   const float* __restrict__ w1,
                                                   const float* __restrict__ st1,
                                                   const float* __restrict__ w2,
                                                   u32* __restrict__ h2p,
                                                   float* __restrict__ part) {
  __shared__ float a1[8][Sn + 2];
  __shared__ float w1s[48], w2s[48], st[16];
  __shared__ float red2s[2][4][2];
  const int t = threadIdx.x;
  if (t < 48) { w1s[t] = w1[t]; w2s[t] = w2[t]; }
  if (t < 16) st[t] = st1[t];
  __syncthreads();
  float s1acc[2] = {0.f, 0.f}, s2acc[2] = {0.f, 0.f};
#pragma unroll
  for (int r4 = 0; r4 < 4; ++r4) {
    const int row = blockIdx.x * 4 + r4;
    const float* xr = x + (size_t)row * Sn * 2;
    const float2 cc = *(const float2*)&xr[2 * t];
    const float2 mm = (t > 0) ? *(const float2*)&xr[2 * t - 2] : make_float2(0.f, 0.f);
    const float2 pp = (t < Sn - 1) ? *(const float2*)&xr[2 * t + 2] : make_float2(0.f, 0.f);
    if (r4) __syncthreads();   // previous row's a1 readers done before overwrite
#pragma unroll
    for (int o = 0; o < 8; ++o) {
      const float* w = &w1s[o * 6];
      float h = w[0] * mm.x + w[1] * cc.x + w[2] * pp.x + w[3] * mm.y + w[4] * cc.y + w[5] * pp.y;
      float v = fmaf(h, st[2 * o], st[2 * o + 1]);
      a1[o][1 + t] = v > 0.f ? v : 0.f;
      if (t == 0) { a1[o][0] = 0.f; a1[o][Sn + 1] = 0.f; }
    }
    __syncthreads();
    float h2v[2];
#pragma unroll
    for (int j = 0; j < 2; ++j) {
      float acc = 0.f;
#pragma unroll
      for (int o = 0; o < 8; ++o) {
        const float* w = &w2s[j * 24 + o * 3];
        acc += w[0] * a1[o][t] + w[1] * a1[o][t + 1] + w[2] * a1[o][t + 2];
      }
      h2v[j] = acc;
    }
    h2p[(size_t)row * Sn + t] = cvtpk(h2v[0], h2v[1]);
#pragma unroll
    for (int j = 0; j < 2; ++j) { s1acc[j] += h2v[j]; s2acc[j] += h2v[j] * h2v[j]; }
  }
  const int lane = t & 63, wv = t >> 6;
#pragma unroll
  for (int j = 0; j < 2; ++j) {
    float v1 = s1acc[j], v2 = s2acc[j];
#pragma unroll
    for (int off = 32; off; off >>= 1) { v1 += __shfl_down(v1, off); v2 += __shfl_down(v2, off); }
    if (lane == 0) { red2s[j][wv][0] = v1; red2s[j][wv][1] = v2; }
  }
  __syncthreads();
  if (t < 2) {
    const float a1s = red2s[t][0][0] + red2s[t][1][0] + red2s[t][2][0] + red2s[t][3][0];
    const float a2s = red2s[t][0][1] + red2s[t][1][1] + red2s[t][2][1] + red2s[t][3][1];
    part[((size_t)t * gridDim.x + blockIdx.x) * 2 + 0] = a1s;
    part[((size_t)t * gridDim.x + blockIdx.x) * 2 + 1] = a2s;
  }
}

// ============================================================================
// DFT prep: BN2+ReLU+sumRX over packed-bf16 h2 -> B1 planes bf16 hi/lo.
// 4 rows per block (amortizes dispatch ramp; same per-element math).
// ============================================================================
__global__ __launch_bounds__(256) void k_prep(const u32* __restrict__ h2p,
                                              const float* __restrict__ st2,
                                              u32* __restrict__ B1h32,
                                              u32* __restrict__ B1l32) {
  const int s = threadIdx.x;
  const float sc0 = st2[0], sh0 = st2[1], sc1 = st2[2], sh1 = st2[3];
#pragma unroll
  for (int r4 = 0; r4 < 4; ++r4) {
    const int row = blockIdx.x * 4 + r4;
    const int b = row >> 7, c = row & (Cn - 1);
    float xr = 0.f, xi = 0.f;
#pragma unroll
    for (int rx = 0; rx < RXn; ++rx) {
      const u32 v = h2p[(((size_t)b * RXn + rx) * Cn + c) * Sn + s];
      const float vr = bf2f((u16)(v & 0xFFFFu));
      const float vi = bf2f((u16)(v >> 16));
      xr += fmaxf(fmaf(vr, sc0, sh0), 0.f);
      xi += fmaxf(fmaf(vi, sc1, sh1), 0.f);
    }
    u32 hi, lo;
    split2(xr, xi, hi, lo);
    B1h32[(size_t)row * 256 + s] = hi;
    B1l32[(size_t)row * 256 + s] = lo;
  }
}

// ============================================================================
// Split-bf16 MFMA GEMM (hi/lo, ~fp32): M32 x N64 tiles, K chunk 32.
// STORE=0: rng -> B2 planes; STORE=1: dop -> rd packed bf16 {re,im} u32
// ============================================================================
template <int M, int N, int K, int STORE>
__global__ __launch_bounds__(256) void k_gemm_split(const u16* __restrict__ Ah,
                                                    const u16* __restrict__ Al,
                                                    const u16* __restrict__ Bh,
                                                    const u16* __restrict__ Bl,
                                                    u32* __restrict__ out0,
                                                    u32* __restrict__ out1) {
  __shared__ __align__(16) u16 lah[32 * 40], lal[32 * 40];
  __shared__ __align__(16) u16 lbh[64 * 40], lbl[64 * 40];
  const int tid = threadIdx.x;
  const int lane = tid & 63, wid = tid >> 6;
  const int wm = wid >> 1, wn = wid & 1;
  const int l15 = lane & 15, lg = lane >> 4;
  const int m0 = blockIdx.x * 32, n0 = blockIdx.y * 64;
  f32x4 acc[2];
  acc[0] = (f32x4){0.f, 0.f, 0.f, 0.f};
  acc[1] = (f32x4){0.f, 0.f, 0.f, 0.f};
  const int arow = tid >> 3, ak = (tid & 7) * 4;
  const int brow = tid >> 2, bk = (tid & 3) * 8;
  for (int k0 = 0; k0 < K; k0 += 32) {
    *(u16x4*)&lah[arow * 40 + ak] = *(const u16x4*)&Ah[(size_t)(m0 + arow) * K + k0 + ak];
    *(u16x4*)&lal[arow * 40 + ak] = *(const u16x4*)&Al[(size_t)(m0 + arow) * K + k0 + ak];
    *(u16x8*)&lbh[brow * 40 + bk] = *(const u16x8*)&Bh[(size_t)(n0 + brow) * K + k0 + bk];
    *(u16x8*)&lbl[brow * 40 + bk] = *(const u16x8*)&Bl[(size_t)(n0 + brow) * K + k0 + bk];
    __syncthreads();
    const bf16x8 ah = *(const bf16x8*)&lah[(wm * 16 + l15) * 40 + lg * 8];
    const bf16x8 al = *(const bf16x8*)&lal[(wm * 16 + l15) * 40 + lg * 8];
#pragma unroll
    for (int f = 0; f < 2; ++f) {
      const bf16x8 bh = *(const bf16x8*)&lbh[(wn * 32 + f * 16 + l15) * 40 + lg * 8];
      const bf16x8 bl = *(const bf16x8*)&lbl[(wn * 32 + f * 16 + l15) * 40 + lg * 8];
      acc[f] = __builtin_amdgcn_mfma_f32_16x16x32_bf16(ah, bh, acc[f], 0, 0, 0);
      acc[f] = __builtin_amdgcn_mfma_f32_16x16x32_bf16(ah, bl, acc[f], 0, 0, 0);
      acc[f] = __builtin_amdgcn_mfma_f32_16x16x32_bf16(al, bh, acc[f], 0, 0, 0);
    }
    __syncthreads();
  }
  const int mb = m0 + wm * 16 + lg * 4;
#pragma unroll
  for (int f = 0; f < 2; ++f) {
    const int n = n0 + wn * 32 + f * 16 + l15;
    if (STORE == 0) {
      const int b = n >> 7, c = n & 127;
#pragma unroll
      for (int pair = 0; pair < 2; ++pair) {
        const int r = (mb >> 1) + pair;
        u32 hi, lo;
        split2(acc[f][2 * pair], acc[f][2 * pair + 1], hi, lo);
        const size_t idx = ((size_t)b * 256 + r) * 128 + c;
        out0[idx] = hi;
        out1[idx] = lo;
      }
    } else {
      const int b = n >> 8, r = n & 255;
#pragma unroll
      for (int pair = 0; pair < 2; ++pair) {
        const int d = (mb >> 1) + pair;
        out0[((size_t)b * 128 + d) * 256 + r] = cvtpk(acc[f][2 * pair], acc[f][2 * pair + 1]);
      }
    }
  }
}

// ============================================================================
// MFMA implicit-GEMM 3x3 conv (pad 1), NHWC bf16 activations (raw), fused:
//   MODE 1: bnrelu(in)                            (dec3)
//   MODE 2: bnrelu(2x2 maxpool of raw)            (enc2, enc3)
//   MODE 3: up2(bnrelu(in @ H/2 x W/2)) + bnrelu(in2 @ H x W)  (dec2, dec1)
// MODE 3: two-phase in-LDS dedup. Phase A computes bnrelu(in_lowres) ONCE
// per low-res pixel of the block's support region into f32 LDS. Phase B
// lerps from LDS + adds skip. Bit-identical math.
// ============================================================================
template <int CIN, int COUT, int H, int W, int TH, int TW, int MW, int NW,
          int WAVES_M, int WAVES_N, int MODE>
__global__ __launch_bounds__(256) void k_conv_mfma(const u16* __restrict__ in,
                                                   const u16* __restrict__ wpk,
                                                   const float* __restrict__ in_stats,
                                                   const u16* __restrict__ in2,
                                                   const float* __restrict__ in2_stats,
                                                   u16* __restrict__ out,
                                                   float* __restrict__ part) {
  constexpr int COG = WAVES_M * MW * 16;
  constexpr int CHUNKS = CIN / 32;
  constexpr int NFROW = TW / 16;
  constexpr int XROWS = TH + 2, XCOLS = TW + 2;
  // MODE 3 support region (TH=8, TW=32, scale ~0.5): rows <= 7, cols <= 19
  constexpr int RR = 7, RC = 19;
  static_assert(WAVES_M * WAVES_N == 4, "waves");
  static_assert(WAVES_N * NW * 16 == TH * TW, "pixel cover");
  static_assert(MODE != 3 || (TH == 8 && TW == 32), "region sized for 8x32");
  __shared__ __align__(16) u16 xs[XROWS * XCOLS * 40];
  __shared__ float red1[WAVES_N][COG], red2[WAVES_N][COG];
  __shared__ __align__(16) float sst1[2 * CIN];
  __shared__ __align__(16) float sst2[(MODE == 3) ? 2 * CIN : 4];
  __shared__ __align__(16) float reg_lds[(MODE == 3) ? RR * RC * 32 : 4];
  const int tid = threadIdx.x;
  const int lane = tid & 63;
  const int wid = tid >> 6;
  const int wave_m = wid / WAVES_N;
  const int wave_n = wid % WAVES_N;
  const int l15 = lane & 15, lg = lane >> 4;
  constexpr int TILES_W = W / TW;
  const int tile = blockIdx.x;
  const int tw = tile % TILES_W, th = tile / TILES_W;
  const int h0 = th * TH, w0 = tw * TW;
  const int cog = blockIdx.y, b = blockIdx.z;
  // preload BN stats into LDS (one barrier; bit-identical copy)
  for (int i = tid; i < 2 * CIN; i += 256) sst1[i] = in_stats[i];
  if (MODE == 3)
    for (int i = tid; i < 2 * CIN; i += 256) sst2[i] = in2_stats[i];
  __syncthreads();
  f32x4 acc[MW][NW];
#pragma unroll
  for (int m = 0; m < MW; ++m)
#pragma unroll
    for (int f = 0; f < NW; ++f) acc[m][f] = (f32x4){0.f, 0.f, 0.f, 0.f};

  for (int q = 0; q < CHUNKS; ++q) {
    // ---- hoisted BN stats (thread-invariant within the item loops) ----
    const int ci0 = (tid & 3) * 8;
    const int cch = q * 32 + ci0;
    float sc[8], sh[8];
#pragma unroll
    for (int k = 0; k < 4; ++k) {
      const float4 qq = *(const float4*)&sst1[2 * cch + 4 * k];
      sc[2 * k] = qq.x; sh[2 * k] = qq.y; sc[2 * k + 1] = qq.z; sh[2 * k + 1] = qq.w;
    }
    float ec[8], es[8];
    if constexpr (MODE == 3) {
#pragma unroll
      for (int k = 0; k < 4; ++k) {
        const float4 qq = *(const float4*)&sst2[2 * cch + 4 * k];
        ec[2 * k] = qq.x; es[2 * k] = qq.y; ec[2 * k + 1] = qq.z; es[2 * k + 1] = qq.w;
      }
    }
    if constexpr (MODE == 3) {
      constexpr int Hi2 = H / 2, Wi2 = W / 2;
      constexpr float steph = (float)(Hi2 - 1) / (float)(H - 1);
      constexpr float stepw = (float)(Wi2 - 1) / (float)(W - 1);
      const int gh_min = (h0 - 1 > 0) ? h0 - 1 : 0;
      const int gw_min = (w0 - 1 > 0) ? w0 - 1 : 0;
      const int lo0 = (int)((float)gh_min * steph);
      const int lw0 = (int)((float)gw_min * stepw);
      // ---- phase A: bnrelu(low-res) once per region pixel -> f32 LDS ----
      for (int i = tid; i < RR * RC * 4; i += 256) {
        const int pixr = i >> 2;
        const int rcc = pixr % RC;
        const int rrr = pixr / RC;
        const int lr = (lo0 + rrr < Hi2 - 1) ? lo0 + rrr : Hi2 - 1;
        const int lc = (lw0 + rcc < Wi2 - 1) ? lw0 + rcc : Wi2 - 1;
        float tv[8];
        ld8bf(&in[(((size_t)b * Hi2 + lr) * Wi2 + lc) * CIN + cch], tv);
#pragma unroll
        for (int k = 0; k < 8; ++k) tv[k] = fmaxf(fmaf(tv[k], sc[k], sh[k]), 0.f);
        *(float4*)&reg_lds[(rrr * RC + rcc) * 32 + ci0] = *(float4*)&tv[0];
        *(float4*)&reg_lds[(rrr * RC + rcc) * 32 + ci0 + 4] = *(float4*)&tv[4];
      }
      __syncthreads();
      // ---- phase B: lerp from LDS + skip bnrelu -> xs ----
      for (int i = tid; i < XROWS * XCOLS * 4; i += 256) {
        const int pix = i >> 2;
        const int col = pix % XCOLS;
        const int row = pix / XCOLS;
        const int gh = h0 + row - 1, gw = w0 + col - 1;
        u32x4 enc = (u32x4){0u, 0u, 0u, 0u};
        if (gh >= 0 && gh < H && gw >= 0 && gw < W) {
          const float ph = (float)gh * steph;
          const int hlo = (int)ph;
          const float fh = ph - (float)hlo;
          const int hhi = (hlo + 1 < Hi2) ? hlo + 1 : Hi2 - 1;
          const float pw = (float)gw * stepw;
          const int wl = (int)pw;
          const float fw = pw - (float)wl;
          const int wh = (wl + 1 < Wi2) ? wl + 1 : Wi2 - 1;
          const float w00 = (1.f - fh) * (1.f - fw), w01 = (1.f - fh) * fw;
          const float w10 = fh * (1.f - fw), w11 = fh * fw;
          const float* p00 = &reg_lds[((hlo - lo0) * RC + (wl - lw0)) * 32 + ci0];
          const float* p01 = &reg_lds[((hlo - lo0) * RC + (wh - lw0)) * 32 + ci0];
          const float* p10 = &reg_lds[((hhi - lo0) * RC + (wl - lw0)) * 32 + ci0];
          const float* p11 = &reg_lds[((hhi - lo0) * RC + (wh - lw0)) * 32 + ci0];
          float ev[8];
          ld8bf(&in2[(((size_t)b * H + gh) * W + gw) * CIN + cch], ev);
          float vv[8];
#pragma unroll
          for (int k = 0; k < 8; ++k) {
            vv[k] = w00 * p00[k] + w01 * p01[k] + w10 * p10[k] + w11 * p11[k]
                  + fmaxf(fmaf(ev[k], ec[k], es[k]), 0.f);
          }
#pragma unroll
          for (int j = 0; j < 4; ++j) enc[j] = cvtpk(vv[2 * j], vv[2 * j + 1]);
        }
        *(u32x4*)&xs[(row * XCOLS + col) * 40 + ci0] = enc;
      }
    } else {
      for (int i = tid; i < XROWS * XCOLS * 4; i += 256) {
        const int pix = i >> 2;
        const int col = pix % XCOLS;
        const int row = pix / XCOLS;
        const int gh = h0 + row - 1, gw = w0 + col - 1;
        u32x4 enc = (u32x4){0u, 0u, 0u, 0u};
        if (gh >= 0 && gh < H && gw >= 0 && gw < W) {
          float vv[8];
          if constexpr (MODE == 1) {
            float tv[8];
            ld8bf(&in[(((size_t)b * H + gh) * W + gw) * CIN + cch], tv);
#pragma unroll
            for (int k = 0; k < 8; ++k) vv[k] = fmaxf(fmaf(tv[k], sc[k], sh[k]), 0.f);
          } else {
            // MODE 2: max of raw taps first, then single BN+ReLU (sc > 0)
            const size_t rs = (size_t)(2 * W) * CIN;
            const u16* pb = &in[(((size_t)b * 2 * H + 2 * gh) * (2 * W) + 2 * gw) * CIN + cch];
            float tp[4][8];
            ld8bf(pb, tp[0]);
            ld8bf(pb + CIN, tp[1]);
            ld8bf(pb + rs, tp[2]);
            ld8bf(pb + rs + CIN, tp[3]);
#pragma unroll
            for (int k = 0; k < 8; ++k) {
              const float mx = fmaxf(fmaxf(tp[0][k], tp[1][k]), fmaxf(tp[2][k], tp[3][k]));
              vv[k] = fmaxf(fmaf(mx, sc[k], sh[k]), 0.f);
            }
          }
#pragma unroll
          for (int j = 0; j < 4; ++j) enc[j] = cvtpk(vv[2 * j], vv[2 * j + 1]);
        }
        *(u32x4*)&xs[(row * XCOLS + col) * 40 + ci0] = enc;
      }
    }
    __syncthreads();
#pragma unroll
    for (int t = 0; t < 9; ++t) {
      const int ky = t / 3, kx = t % 3;
      bf16x8 afr[MW];
#pragma unroll
      for (int m = 0; m < MW; ++m) {
        const int mfg = cog * (COG / 16) + wave_m * MW + m;
        afr[m] = *(const bf16x8*)&wpk[((((size_t)mfg * CHUNKS + q) * 9 + t) * 64 + lane) * 8];
      }
      bf16x8 bfr[NW];
#pragma unroll
      for (int f = 0; f < NW; ++f) {
        const int nf = wave_n * NW + f;
        const int r = nf / NFROW;
        const int cseg = (nf % NFROW) * 16;
        bfr[f] = *(const bf16x8*)&xs[((r + ky) * XCOLS + (cseg + l15 + kx)) * 40 + lg * 8];
      }
#pragma unroll
      for (int m = 0; m < MW; ++m)
#pragma unroll
        for (int f = 0; f < NW; ++f)
          acc[m][f] = __builtin_amdgcn_mfma_f32_16x16x32_bf16(afr[m], bfr[f], acc[m][f], 0, 0, 0);
    }
    __syncthreads();
  }

#pragma unroll
  for (int m = 0; m < MW; ++m) {
    const int cobase = cog * COG + (wave_m * MW + m) * 16 + lg * 4;
#pragma unroll
    for (int f = 0; f < NW; ++f) {
      const int nf = wave_n * NW + f;
      const int r = nf / NFROW;
      const int cseg = (nf % NFROW) * 16;
      u16* op = out + (((size_t)b * H + h0 + r) * W + (w0 + cseg + l15)) * COUT + cobase;
      u32x2 ov;
      ov[0] = cvtpk(acc[m][f][0], acc[m][f][1]);
      ov[1] = cvtpk(acc[m][f][2], acc[m][f][3]);
      *(u32x2*)op = ov;
    }
  }
#pragma unroll
  for (int m = 0; m < MW; ++m)
#pragma unroll
    for (int reg = 0; reg < 4; ++reg) {
      float s1 = 0.f, s2 = 0.f;
#pragma unroll
      for (int f = 0; f < NW; ++f) { const float v = acc[m][f][reg]; s1 += v; s2 += v * v; }
#pragma unroll
      for (int off = 1; off < 16; off <<= 1) { s1 += __shfl_xor(s1, off); s2 += __shfl_xor(s2, off); }
      if (l15 == 0) {
        const int ch = (wave_m * MW + m) * 16 + lg * 4 + reg;
        red1[wave_n][ch] = s1; red2[wave_n][ch] = s2;
      }
    }
  __syncthreads();
  if (tid < COG) {
    float s1 = 0.f, s2 = 0.f;
#pragma unroll
    for (int wn = 0; wn < WAVES_N; ++wn) { s1 += red1[wn][tid]; s2 += red2[wn][tid]; }
    const int npart = gridDim.x * gridDim.z;
    const int pidx = blockIdx.z * gridDim.x + blockIdx.x;
    part[((size_t)(cog * COG + tid) * npart + pidx) * 2 + 0] = s1;
    part[((size_t)(cog * COG + tid) * npart + pidx) * 2 + 1] = s2;
  }
}

// ============================================================================
// enc1 direct fp32 conv: packed-bf16 rd in (C=2) -> NHWC out (C=32 bf16)
// ============================================================================
__global__ __launch_bounds__(256) void k_conv1(const u32* __restrict__ in,
                                               const float* __restrict__ wgt,
                                               u16* __restrict__ out,
                                               float* __restrict__ part) {
  constexpr int H = 128, W = 256, TW = 64, TH = 16, COG = 16, COUT = 32;
  const int tid = threadIdx.x;
  const int tile = blockIdx.x;
  const int tw = tile & 3, th = tile >> 2;
  const int cog = blockIdx.y, b = blockIdx.z;
  const int ty = tid >> 4;
  const int wofs = (tid & 15) * 4;
  const int h0 = th * TH, w0t = tw * TW;
  __shared__ float xs0[TH + 2][TW + 3], xs1[TH + 2][TW + 3];
  __shared__ float ws[2][COG][12];
  __shared__ float redp[4][COG], redq[4][COG];
  for (int i = tid; i < 2 * COG * 9; i += 256) {
    const int tap = i % 9, rest = i / 9;
    const int ci = rest & 1, co = rest >> 1;
    ws[ci][co][tap] = wgt[((size_t)(cog * COG + co) * 2 + ci) * 9 + tap];
  }
  for (int i = tid; i < (TH + 2) * (TW + 2); i += 256) {
    const int col = i % (TW + 2), row = i / (TW + 2);
    const int gh = h0 + row - 1, gw = w0t + col - 1;
    float v0 = 0.f, v1 = 0.f;
    if (gh >= 0 && gh < H && gw >= 0 && gw < W) {
      const u32 v = in[((size_t)b * H + gh) * W + gw];
      v0 = bf2f((u16)(v & 0xFFFFu));
      v1 = bf2f((u16)(v >> 16));
    }
    xs0[row][col] = v0; xs1[row][col] = v1;
  }
  __syncthreads();
  float acc[4][COG];
#pragma unroll
  for (int px = 0; px < 4; ++px)
#pragma unroll
    for (int co = 0; co < COG; ++co) acc[px][co] = 0.f;
#pragma unroll
  for (int ci = 0; ci < 2; ++ci) {
    float xrow[3][6];
#pragma unroll
    for (int ky = 0; ky < 3; ++ky)
#pragma unroll
      for (int j = 0; j < 6; ++j)
        xrow[ky][j] = ci ? xs1[ty + ky][wofs + j] : xs0[ty + ky][wofs + j];
#pragma unroll
    for (int co = 0; co < COG; ++co) {
      const float4 wq0 = *(const float4*)&ws[ci][co][0];
      const float4 wq1 = *(const float4*)&ws[ci][co][4];
      const float  w8 = ws[ci][co][8];
      const float wv[9] = {wq0.x, wq0.y, wq0.z, wq0.w, wq1.x, wq1.y, wq1.z, wq1.w, w8};
#pragma unroll
      for (int ky = 0; ky < 3; ++ky)
#pragma unroll
        for (int kx = 0; kx < 3; ++kx)
#pragma unroll
          for (int px = 0; px < 4; ++px)
            acc[px][co] = fmaf(xrow[ky][px + kx], wv[ky * 3 + kx], acc[px][co]);
    }
  }
#pragma unroll
  for (int px = 0; px < 4; ++px) {
    u16* op = out + (((size_t)b * H + h0 + ty) * W + (w0t + wofs + px)) * COUT + cog * COG;
    u32x4 ov;
    ov[0] = cvtpk(acc[px][0], acc[px][1]);
    ov[1] = cvtpk(acc[px][2], acc[px][3]);
    ov[2] = cvtpk(acc[px][4], acc[px][5]);
    ov[3] = cvtpk(acc[px][6], acc[px][7]);
    *(u32x4*)&op[0] = ov;
    u32x4 ov2;
    ov2[0] = cvtpk(acc[px][8], acc[px][9]);
    ov2[1] = cvtpk(acc[px][10], acc[px][11]);
    ov2[2] = cvtpk(acc[px][12], acc[px][13]);
    ov2[3] = cvtpk(acc[px][14], acc[px][15]);
    *(u32x4*)&op[8] = ov2;
  }
  const int lane = tid & 63, wid = tid >> 6;
#pragma unroll
  for (int co = 0; co < COG; ++co) {
    float v1 = 0.f, v2 = 0.f;
#pragma unroll
    for (int px = 0; px < 4; ++px) { v1 += acc[px][co]; v2 += acc[px][co] * acc[px][co]; }
#pragma unroll
    for (int off = 32; off; off >>= 1) { v1 += __shfl_down(v1, off); v2 += __shfl_down(v2, off); }
    if (lane == 0) { redp[wid][co] = v1; redq[wid][co] = v2; }
  }
  __syncthreads();
  if (tid < COG) {
    const int npart = gridDim.x * gridDim.z;
    const int pidx = blockIdx.z * gridDim.x + blockIdx.x;
    part[((size_t)(cog * COG + tid) * npart + pidx) * 2 + 0] = redp[0][tid] + redp[1][tid] + redp[2][tid] + redp[3][tid];
    part[((size_t)(cog * COG + tid) * npart + pidx) * 2 + 1] = redq[0][tid] + redq[1][tid] + redq[2][tid] + redq[3][tid];
  }
}

// final: bnrelu(d1 bf16) -> 1x1 conv (16->1) + bias + sigmoid.
// 4 outputs per thread (512 blocks); stats/weights hoisted to registers.
__global__ __launch_bounds__(256) void k_out_bn(const u16* __restrict__ d1,
                                                const float* __restrict__ st,
                                                const float* __restrict__ ow,
                                                const float* __restrict__ ob,
                                                float* __restrict__ out) {
  const int t = threadIdx.x;
  float qs[16], qh[16], qw[16];
#pragma unroll
  for (int k = 0; k < 16; ++k) {
    const float2 q = *(const float2*)&st[2 * k];
    qs[k] = q.x; qh[k] = q.y; qw[k] = ow[k];
  }
  const float bias = ob[0];
#pragma unroll
  for (int r4 = 0; r4 < 4; ++r4) {
    const size_t i = (size_t)blockIdx.x * 1024 + r4 * 256 + t;
    const u16* p = d1 + i * 16;
    float v[16];
    ld8bf(p, v);
    ld8bf(p + 8, v + 8);
    float acc = bias;
#pragma unroll
    for (int k = 0; k < 16; ++k)
      acc += fmaxf(fmaf(v[k], qs[k], qh[k]), 0.f) * qw[k];
    out[i] = 1.f / (1.f + expf(-acc));
  }
}

// ============================================================================
extern "C" void kernel_launch(void* const* d_in, const int* in_sizes, int n_in,
                              void* d_out, int out_size, void* d_ws, size_t ws_size,
                              hipStream_t stream) {
  (void)in_sizes; (void)n_in; (void)out_size; (void)ws_size;
  const float* x       = (const float*)d_in[0];
  const float* tp_w1   = (const float*)d_in[1];
  const float* tp_g1   = (const float*)d_in[3];
  const float* tp_be1  = (const float*)d_in[4];
  const float* tp_w2   = (const float*)d_in[5];
  const float* tp_g2   = (const float*)d_in[7];
  const float* tp_be2  = (const float*)d_in[8];
  const float* range_w = (const float*)d_in[9];
  const float* dopp_w  = (const float*)d_in[10];
  const float* e1w = (const float*)d_in[11]; const float* e1g = (const float*)d_in[13]; const float* e1b = (const float*)d_in[14];
  const float* e2w = (const float*)d_in[15]; const float* e2g = (const float*)d_in[17]; const float* e2b = (const float*)d_in[18];
  const float* e3w = (const float*)d_in[19]; const float* e3g = (const float*)d_in[21]; const float* e3b = (const float*)d_in[22];
  const float* d3w = (const float*)d_in[23]; const float* d3g = (const float*)d_in[25]; const float* d3b = (const float*)d_in[26];
  const float* d2w = (const float*)d_in[27]; const float* d2g = (const float*)d_in[29]; const float* d2b = (const float*)d_in[30];
  const float* d1w = (const float*)d_in[31]; const float* d1g = (const float*)d_in[33]; const float* d1b = (const float*)d_in[34];
  const float* out_w = (const float*)d_in[35];
  const float* out_b = (const float*)d_in[36];
  float* outp = (float*)d_out;

  // -------- workspace arena; U-Net raw tensors bf16 NHWC --------
  float* W  = (float*)d_ws;
  u16* Ae1  = (u16*)W;
  float* Bx = W + 16777216;
  u16* Ce2  = (u16*)(W + 33554432);
  u16* Ee3  = (u16*)(W + 41943040);
  u16* Fd3  = (u16*)(W + 46137344);
  float* part  = W + 48234496;
  float* stats = part + 262144;
  u16* wpk_e2 = (u16*)(stats + 1024);
  u16* wpk_e3 = wpk_e2 + 18432;
  u16* wpk_d3 = wpk_e3 + 73728;
  u16* wpk_d2 = wpk_d3 + 73728;
  u16* wpk_d1 = wpk_d2 + 18432;
  u16* A1h = wpk_d1 + 4608;
  u16* A1l = A1h + 262144;
  u16* A2h = A1l + 262144;
  u16* A2l = A2h + 65536;
  u16* B1h = A2l + 65536;
  u16* B1l = B1h + 1048576;
  u16* B2h = B1l + 1048576;
  u16* B2l = B2h + 1048576;

  u32* h2p = (u32*)Bx;                         // [8192][256] packed bf16 pairs (8MB)
  u32* rd  = (u32*)(Bx + 2097152 + 65536);     // [b][128][256] packed {re,im} (2MB)
  u16* d1  = (u16*)Bx;                         // [b][128][256][16] bf16 (h2p/rd dead)

  float* st_tp1 = stats;
  float* st_tp2 = stats + 16;
  float* st_e1  = stats + 32;
  float* st_e2  = stats + 96;
  float* st_e3  = stats + 224;
  float* st_d3  = stats + 480;
  float* st_d2  = stats + 608;
  float* st_d1  = stats + 672;

  const float Ntp = 2097152.f;

  // ---- merged head: weight packing (blocks 0-127) || tp stats1 (128-1151) ----
  k_pack_stats<<<1152, 256, 0, stream>>>(e2w, e3w, d3w, d2w, d1w, range_w, dopp_w,
                                         wpk_e2, wpk_e3, wpk_d3, wpk_d2, wpk_d1,
                                         A1h, A1l, A2h, A2l,
                                         x, tp_w1, part);
  k_finalize<<<8, 256, 0, stream>>>(part, 1024, Ntp, tp_g1, tp_be1, st_tp1);
  k_tp_fused2<<<Bn * RXn * Cn / 4, 256, 0, stream>>>(x, tp_w1, st_tp1, tp_w2, h2p, part);
  k_finalize<<<2, 256, 0, stream>>>(part, Bn * RXn * Cn / 4, Ntp, tp_g2, tp_be2, st_tp2);

  // ---- DFTs via split-bf16 MFMA GEMMs ----
  k_prep<<<Bn * Cn / 4, 256, 0, stream>>>(h2p, st_tp2, (u32*)B1h, (u32*)B1l);
  k_gemm_split<512, 2048, 512, 0><<<dim3(16, 32), 256, 0, stream>>>(
      A1h, A1l, B1h, B1l, (u32*)B2h, (u32*)B2l);
  k_gemm_split<256, 4096, 256, 1><<<dim3(8, 64), 256, 0, stream>>>(
      A2h, A2l, B2h, B2l, rd, nullptr);

  // ---- U-Net ----
  k_conv1<<<dim3(32, 2, Bn), 256, 0, stream>>>(rd, e1w, Ae1, part);
  k_finalize<<<32, 256, 0, stream>>>(part, 512, 524288.f, e1g, e1b, st_e1);
  k_conv_mfma<32, 64, 64, 128, 8, 32, 2, 8, 2, 2, 2><<<dim3(32, 1, Bn), 256, 0, stream>>>(
      Ae1, wpk_e2, st_e1, nullptr, nullptr, Ce2, part);
  k_finalize<<<64, 256, 0, stream>>>(part, 512, 131072.f, e2g, e2b, st_e2);
  k_conv_mfma<64, 128, 32, 64, 4, 16, 1, 4, 4, 1, 2><<<dim3(32, 2, Bn), 256, 0, stream>>>(
      Ce2, wpk_e3, st_e2, nullptr, nullptr, Ee3, part);
  k_finalize<<<128, 256, 0, stream>>>(part, 512, 32768.f, e3g, e3b, st_e3);
  k_conv_mfma<128, 64, 32, 64, 4, 16, 1, 4, 4, 1, 1><<<dim3(32, 1, Bn), 256, 0, stream>>>(
      Ee3, wpk_d3, st_e3, nullptr, nullptr, Fd3, part);
  k_finalize<<<64, 256, 0, stream>>>(part, 512, 32768.f, d3g, d3b, st_d3);
  k_conv_mfma<64, 32, 64, 128, 8, 32, 1, 8, 2, 2, 3><<<dim3(32, 1, Bn), 256, 0, stream>>>(
      Fd3, wpk_d2, st_d3, Ce2, st_e2, Ee3, part);
  k_finalize<<<32, 256, 0, stream>>>(part, 512, 131072.f, d2g, d2b, st_d2);
  k_conv_mfma<32, 16, 128, 256, 8, 32, 1, 4, 1, 4, 3><<<dim3(128, 1, Bn), 256, 0, stream>>>(
      Ee3, wpk_d1, st_d2, Ae1, st_e1, d1, part);
  k_finalize<<<16, 256, 0, stream>>>(part, 2048, 524288.f, d1g, d1b, st_d1);
  k_out_bn<<<512, 256, 0, stream>>>(d1, st_d1, out_w, out_b, outp);
}